// Round 2
// baseline (2565.777 us; speedup 1.0000x reference)
//
#include <hip/hip_runtime.h>
#include <hip/hip_bf16.h>
#include <math.h>

// ---------------------------------------------------------------------------
// FastAttention (Performer/SORF linear attention), fp32, ws-size-adaptive.
// Path A (ws >= ~142MB): two-pass QKV GEMM with buffer reuse:
//   k_build_at -> At ; k_qkv(K,V) -> buf1,buf2 ; k_kvstats -> S,sumk ;
//   k_qkv(Q) -> buf1 ; k_attn -> buf2 ; k_outgemm -> out
// Path B (small ws, ~5.3MB): fused recompute fallback:
//   k_build_at ; k_kv_fused (recompute k,v per head on the fly) -> S,sumk ;
//   k_q_fused (recompute q, phi, numer/denom, atomic out GEMM) -> out
// ---------------------------------------------------------------------------

#define LOG2_10000 13.287712379549449f

__global__ __launch_bounds__(256) void k_zero(float* __restrict__ p, size_t n) {
    size_t i = (size_t)blockIdx.x * 256 + threadIdx.x;
    const size_t st = (size_t)gridDim.x * 256;
    for (; i < n; i += st) p[i] = 0.0f;
}

// ------------------------- kernel: build At --------------------------------
__global__ __launch_bounds__(64) void k_build_at(const float* __restrict__ signs,
                                                 const float* __restrict__ scales,
                                                 float* __restrict__ At) {
    const int b  = blockIdx.x;      // h*4 + r
    const int hh = b >> 2, r = b & 3;
    const int j  = threadIdx.x;     // input dim (column of A), 0..63
    const float* s1 = signs + ((size_t)(hh * 4 + r) * 3 + 0) * 64;
    const float* s2 = s1 + 64;
    const float* s3 = s1 + 128;
    const float* sc = scales + (size_t)(hh * 4 + r) * 64;

    float v[64];
    const float s1j = s1[j];
#pragma unroll
    for (int p = 0; p < 64; ++p) v[p] = (p == j) ? s1j : 0.0f;

#pragma unroll
    for (int st = 1; st < 64; st <<= 1) {
#pragma unroll
        for (int p = 0; p < 64; ++p) {
            if (!(p & st)) {
                float a = v[p], bq = v[p | st];
                v[p] = a + bq;
                v[p | st] = a - bq;
            }
        }
    }
#pragma unroll
    for (int p = 0; p < 64; ++p) v[p] *= s2[p];
#pragma unroll
    for (int st = 1; st < 64; st <<= 1) {
#pragma unroll
        for (int p = 0; p < 64; ++p) {
            if (!(p & st)) {
                float a = v[p], bq = v[p | st];
                v[p] = a + bq;
                v[p | st] = a - bq;
            }
        }
    }
#pragma unroll
    for (int p = 0; p < 64; ++p) v[p] *= s3[p];
#pragma unroll
    for (int st = 1; st < 64; st <<= 1) {
#pragma unroll
        for (int p = 0; p < 64; ++p) {
            if (!(p & st)) {
                float a = v[p], bq = v[p | st];
                v[p] = a + bq;
                v[p | st] = a - bq;
            }
        }
    }
    float* dst = At + ((size_t)(hh * 64 + j)) * 256 + r * 64;
#pragma unroll
    for (int p = 0; p < 64; ++p) dst[p] = v[p] * sc[p] * (1.0f / 4096.0f);
}

// ------------------------- kernel: QKV GEMM + RoPE -------------------------
// Computes cols [n_base, n_base + gridDim.x*128) of qkv = x@W^T, fused RoPE,
// scatter to (C,H,L,D), atomic norm accumulation.
__global__ __launch_bounds__(256) void k_qkv(const float* __restrict__ X,
                                             const float* __restrict__ W,
                                             float* __restrict__ qr,
                                             float* __restrict__ kr,
                                             float* __restrict__ vv,
                                             float* __restrict__ nq,
                                             float* __restrict__ nk,
                                             int n_base) {
    __shared__ float As[16][128];
    __shared__ float Bs[16][128];
    const int tid = threadIdx.x;
    const int bm = blockIdx.y, bn = blockIdx.x;
    const int m0 = bm * 128, n0 = n_base + bn * 128;
    const int lr = tid >> 1;            // 0..127 tile row
    const int lc = (tid & 1) * 8;       // 0 or 8
    const float* Arow = X + (size_t)(m0 + lr) * 1024 + lc;
    const float* Brow = W + (size_t)(n0 + lr) * 1024 + lc;
    const int tm = (tid & 15) * 8;
    const int tn = (tid >> 4) * 8;
    float acc[8][8] = {};

    for (int kt = 0; kt < 1024; kt += 16) {
        const float4 a0 = *(const float4*)(Arow + kt);
        const float4 a1 = *(const float4*)(Arow + kt + 4);
        const float4 b0 = *(const float4*)(Brow + kt);
        const float4 b1 = *(const float4*)(Brow + kt + 4);
        __syncthreads();
        As[lc + 0][lr] = a0.x; As[lc + 1][lr] = a0.y; As[lc + 2][lr] = a0.z; As[lc + 3][lr] = a0.w;
        As[lc + 4][lr] = a1.x; As[lc + 5][lr] = a1.y; As[lc + 6][lr] = a1.z; As[lc + 7][lr] = a1.w;
        Bs[lc + 0][lr] = b0.x; Bs[lc + 1][lr] = b0.y; Bs[lc + 2][lr] = b0.z; Bs[lc + 3][lr] = b0.w;
        Bs[lc + 4][lr] = b1.x; Bs[lc + 5][lr] = b1.y; Bs[lc + 6][lr] = b1.z; Bs[lc + 7][lr] = b1.w;
        __syncthreads();
#pragma unroll
        for (int k = 0; k < 16; ++k) {
            const float4 x0 = *(const float4*)&As[k][tm];
            const float4 x1 = *(const float4*)&As[k][tm + 4];
            const float4 y0 = *(const float4*)&Bs[k][tn];
            const float4 y1 = *(const float4*)&Bs[k][tn + 4];
            const float xa[8] = {x0.x, x0.y, x0.z, x0.w, x1.x, x1.y, x1.z, x1.w};
            const float yb[8] = {y0.x, y0.y, y0.z, y0.w, y1.x, y1.y, y1.z, y1.w};
#pragma unroll
            for (int i = 0; i < 8; ++i)
#pragma unroll
                for (int j = 0; j < 8; ++j) acc[i][j] = fmaf(xa[i], yb[j], acc[i][j]);
        }
    }

    const int col0 = n0 + tn;
    const int sec = col0 >> 10;          // 0=q 1=k 2=v (uniform per block)
    const int hh = (col0 & 1023) >> 6;
    const int d0 = col0 & 63;
    float* tgt = (sec == 0) ? qr : (sec == 1) ? kr : vv;
    float* ntgt = (sec == 0) ? nq : nk;

#pragma unroll
    for (int i = 0; i < 8; ++i) {
        const int gm = m0 + tm + i;
        const int c = gm >> 12, l = gm & 4095;
        float vals[8];
#pragma unroll
        for (int j = 0; j < 8; ++j) vals[j] = acc[i][j];
        if (sec < 2 && l > 0) {
            const float pos = (float)(l - 1);
#pragma unroll
            for (int p = 0; p < 4; ++p) {
                const int dd = d0 + 2 * p;
                const float freq = exp2f(-(float)dd * (LOG2_10000 / 64.0f));
                const float ang = pos * freq;
                float sn, cs;
                sincosf(ang, &sn, &cs);
                const float t1 = vals[2 * p], t2 = vals[2 * p + 1];
                vals[2 * p] = t1 * cs - t2 * sn;
                vals[2 * p + 1] = t1 * sn + t2 * cs;
            }
        }
        const size_t base = ((size_t)((c * 16 + hh) * 4096 + l)) * 64 + d0;
        *(float4*)(tgt + base) = make_float4(vals[0], vals[1], vals[2], vals[3]);
        *(float4*)(tgt + base + 4) = make_float4(vals[4], vals[5], vals[6], vals[7]);
        if (sec < 2) {
            float ss = 0.f;
#pragma unroll
            for (int j = 0; j < 8; ++j) ss += vals[j] * vals[j];
            atomicAdd(ntgt + (size_t)(c * 16 + hh) * 4096 + l, ss * 0.5f);
        }
    }
}

// ------------------------- kernel: kphi -> S, sumk -------------------------
__global__ __launch_bounds__(256) void k_kvstats(const float* __restrict__ kr,
                                                 const float* __restrict__ vv,
                                                 const float* __restrict__ nk,
                                                 const float* __restrict__ At,
                                                 float* __restrict__ S,
                                                 float* __restrict__ sumk) {
    const int ch = blockIdx.x;
    const int h = ch & 15;
    const int split = blockIdx.y;
    const int tid = threadIdx.x;
    __shared__ float Krst[64][36];
    __shared__ float Vs[32][64];
    __shared__ float Kph[32][260];
    __shared__ float nks[32];
    const float* Krb = kr + (size_t)ch * 4096 * 64;
    const float* Vb = vv + (size_t)ch * 4096 * 64;
    const float* Ab = At + (size_t)h * 64 * 256;
    float Sacc[8][8] = {};
    float skacc[8] = {};
    const int tl = tid >> 6, tf = tid & 63;
    const int tf2 = tid & 31, dg = tid >> 5;

    for (int chunk = 0; chunk < 16; ++chunk) {
        const int l0 = split * 512 + chunk * 32;
        __syncthreads();
        {
            const int rrow = tid >> 4, c4 = (tid & 15) * 4;
#pragma unroll
            for (int rr = 0; rr < 32; rr += 16) {
                const float4 kv = *(const float4*)&Krb[(size_t)(l0 + rrow + rr) * 64 + c4];
                Krst[c4 + 0][rrow + rr] = kv.x;
                Krst[c4 + 1][rrow + rr] = kv.y;
                Krst[c4 + 2][rrow + rr] = kv.z;
                Krst[c4 + 3][rrow + rr] = kv.w;
                *(float4*)&Vs[rrow + rr][c4] = *(const float4*)&Vb[(size_t)(l0 + rrow + rr) * 64 + c4];
            }
            if (tid < 32) nks[tid] = nk[(size_t)ch * 4096 + l0 + tid];
        }
        __syncthreads();
        float pacc[8][4] = {};
        for (int d = 0; d < 64; ++d) {
            const float4 av = *(const float4*)&Ab[d * 256 + tf * 4];
            const float4 k0 = *(const float4*)&Krst[d][tl * 8];
            const float4 k1 = *(const float4*)&Krst[d][tl * 8 + 4];
            const float ka[8] = {k0.x, k0.y, k0.z, k0.w, k1.x, k1.y, k1.z, k1.w};
            const float ab4[4] = {av.x, av.y, av.z, av.w};
#pragma unroll
            for (int i = 0; i < 8; ++i)
#pragma unroll
                for (int j = 0; j < 4; ++j) pacc[i][j] = fmaf(ka[i], ab4[j], pacc[i][j]);
        }
#pragma unroll
        for (int i = 0; i < 8; ++i) {
            const float n = nks[tl * 8 + i];
            float4 kp;
            kp.x = expf(pacc[i][0] - n) * 0.0625f;
            kp.y = expf(pacc[i][1] - n) * 0.0625f;
            kp.z = expf(pacc[i][2] - n) * 0.0625f;
            kp.w = expf(pacc[i][3] - n) * 0.0625f;
            *(float4*)&Kph[tl * 8 + i][tf * 4] = kp;
        }
        __syncthreads();
#pragma unroll 4
        for (int l = 0; l < 32; ++l) {
            const float4 a0 = *(const float4*)&Kph[l][tf2 * 8];
            const float4 a1 = *(const float4*)&Kph[l][tf2 * 8 + 4];
            const float4 b0 = *(const float4*)&Vs[l][dg * 8];
            const float4 b1 = *(const float4*)&Vs[l][dg * 8 + 4];
            const float fa[8] = {a0.x, a0.y, a0.z, a0.w, a1.x, a1.y, a1.z, a1.w};
            const float fb[8] = {b0.x, b0.y, b0.z, b0.w, b1.x, b1.y, b1.z, b1.w};
#pragma unroll
            for (int i = 0; i < 8; ++i)
#pragma unroll
                for (int j = 0; j < 8; ++j) Sacc[i][j] = fmaf(fa[i], fb[j], Sacc[i][j]);
            if (dg == 0) {
#pragma unroll
                for (int i = 0; i < 8; ++i) skacc[i] += fa[i];
            }
        }
    }
    float* Sb = S + (size_t)ch * 256 * 64;
#pragma unroll
    for (int i = 0; i < 8; ++i)
#pragma unroll
        for (int j = 0; j < 8; ++j)
            atomicAdd(&Sb[(size_t)(tf2 * 8 + i) * 64 + dg * 8 + j], Sacc[i][j]);
    if (dg == 0) {
#pragma unroll
        for (int i = 0; i < 8; ++i) atomicAdd(&sumk[(size_t)ch * 256 + tf2 * 8 + i], skacc[i]);
    }
}

// ------------------------- kernel: qphi@S, denom, out_heads ----------------
__global__ __launch_bounds__(256) void k_attn(const float* __restrict__ qr,
                                              const float* __restrict__ nq,
                                              const float* __restrict__ At,
                                              const float* __restrict__ S,
                                              const float* __restrict__ sumk,
                                              float* __restrict__ oh) {
    const int ch = blockIdx.x;
    const int lb = blockIdx.y;
    const int h = ch & 15, c = ch >> 4;
    const int tid = threadIdx.x;
    __shared__ float Qrst[64][36];
    __shared__ float Qph[32][260];
    __shared__ float nqs[32];
    __shared__ float sks[256];
    const int l0 = lb * 32;
    const float* Qb = qr + (size_t)ch * 4096 * 64;
    const float* Ab = At + (size_t)h * 64 * 256;
    const float* Sb = S + (size_t)ch * 256 * 64;

    {
        const int rrow = tid >> 4, c4 = (tid & 15) * 4;
#pragma unroll
        for (int rr = 0; rr < 32; rr += 16) {
            const float4 qv = *(const float4*)&Qb[(size_t)(l0 + rrow + rr) * 64 + c4];
            Qrst[c4 + 0][rrow + rr] = qv.x;
            Qrst[c4 + 1][rrow + rr] = qv.y;
            Qrst[c4 + 2][rrow + rr] = qv.z;
            Qrst[c4 + 3][rrow + rr] = qv.w;
        }
        if (tid < 32) nqs[tid] = nq[(size_t)ch * 4096 + l0 + tid];
        sks[tid] = sumk[(size_t)ch * 256 + tid];
    }
    __syncthreads();
    {
        const int tl = tid >> 6, tf = tid & 63;
        float pacc[8][4] = {};
        for (int d = 0; d < 64; ++d) {
            const float4 av = *(const float4*)&Ab[d * 256 + tf * 4];
            const float4 k0 = *(const float4*)&Qrst[d][tl * 8];
            const float4 k1 = *(const float4*)&Qrst[d][tl * 8 + 4];
            const float ka[8] = {k0.x, k0.y, k0.z, k0.w, k1.x, k1.y, k1.z, k1.w};
            const float ab4[4] = {av.x, av.y, av.z, av.w};
#pragma unroll
            for (int i = 0; i < 8; ++i)
#pragma unroll
                for (int j = 0; j < 4; ++j) pacc[i][j] = fmaf(ka[i], ab4[j], pacc[i][j]);
        }
#pragma unroll
        for (int i = 0; i < 8; ++i) {
            const float n = nqs[tl * 8 + i];
            float4 kp;
            kp.x = expf(pacc[i][0] - n) * 0.0625f;
            kp.y = expf(pacc[i][1] - n) * 0.0625f;
            kp.z = expf(pacc[i][2] - n) * 0.0625f;
            kp.w = expf(pacc[i][3] - n) * 0.0625f;
            *(float4*)&Qph[tl * 8 + i][tf * 4] = kp;
        }
    }
    __syncthreads();
    {
        const int dgf = tid & 7, lf = tid >> 3;
        float num[8] = {};
        float dn = 0.f;
        for (int f = 0; f < 256; ++f) {
            const float qv = Qph[lf][f];
            const float4 s0 = *(const float4*)&Sb[(size_t)f * 64 + dgf * 8];
            const float4 s1 = *(const float4*)&Sb[(size_t)f * 64 + dgf * 8 + 4];
            num[0] = fmaf(qv, s0.x, num[0]);
            num[1] = fmaf(qv, s0.y, num[1]);
            num[2] = fmaf(qv, s0.z, num[2]);
            num[3] = fmaf(qv, s0.w, num[3]);
            num[4] = fmaf(qv, s1.x, num[4]);
            num[5] = fmaf(qv, s1.y, num[5]);
            num[6] = fmaf(qv, s1.z, num[6]);
            num[7] = fmaf(qv, s1.w, num[7]);
            dn = fmaf(qv, sks[f], dn);
        }
        const float rden = 1.0f / fmaxf(dn, 1e-6f);
        const size_t ob = ((size_t)c * 4096 + l0 + lf) * 1024 + h * 64 + dgf * 8;
        *(float4*)&oh[ob] = make_float4(num[0] * rden, num[1] * rden, num[2] * rden, num[3] * rden);
        *(float4*)&oh[ob + 4] = make_float4(num[4] * rden, num[5] * rden, num[6] * rden, num[7] * rden);
    }
}

// ------------------------- kernel: final GEMM ------------------------------
__global__ __launch_bounds__(256) void k_outgemm(const float* __restrict__ OH,
                                                 const float* __restrict__ W,
                                                 float* __restrict__ OUT) {
    __shared__ float As[16][128];
    __shared__ float Bs[16][128];
    const int tid = threadIdx.x;
    const int bm = blockIdx.y, bn = blockIdx.x;
    const int m0 = bm * 128, n0 = bn * 128;
    const int lr = tid >> 1;
    const int lc = (tid & 1) * 8;
    const float* Arow = OH + (size_t)(m0 + lr) * 1024 + lc;
    const float* Brow = W + (size_t)(n0 + lr) * 1024 + lc;
    const int tm = (tid & 15) * 8;
    const int tn = (tid >> 4) * 8;
    float acc[8][8] = {};

    for (int kt = 0; kt < 1024; kt += 16) {
        const float4 a0 = *(const float4*)(Arow + kt);
        const float4 a1 = *(const float4*)(Arow + kt + 4);
        const float4 b0 = *(const float4*)(Brow + kt);
        const float4 b1 = *(const float4*)(Brow + kt + 4);
        __syncthreads();
        As[lc + 0][lr] = a0.x; As[lc + 1][lr] = a0.y; As[lc + 2][lr] = a0.z; As[lc + 3][lr] = a0.w;
        As[lc + 4][lr] = a1.x; As[lc + 5][lr] = a1.y; As[lc + 6][lr] = a1.z; As[lc + 7][lr] = a1.w;
        Bs[lc + 0][lr] = b0.x; Bs[lc + 1][lr] = b0.y; Bs[lc + 2][lr] = b0.z; Bs[lc + 3][lr] = b0.w;
        Bs[lc + 4][lr] = b1.x; Bs[lc + 5][lr] = b1.y; Bs[lc + 6][lr] = b1.z; Bs[lc + 7][lr] = b1.w;
        __syncthreads();
#pragma unroll
        for (int k = 0; k < 16; ++k) {
            const float4 x0 = *(const float4*)&As[k][tm];
            const float4 x1 = *(const float4*)&As[k][tm + 4];
            const float4 y0 = *(const float4*)&Bs[k][tn];
            const float4 y1 = *(const float4*)&Bs[k][tn + 4];
            const float xa[8] = {x0.x, x0.y, x0.z, x0.w, x1.x, x1.y, x1.z, x1.w};
            const float yb[8] = {y0.x, y0.y, y0.z, y0.w, y1.x, y1.y, y1.z, y1.w};
#pragma unroll
            for (int i = 0; i < 8; ++i)
#pragma unroll
                for (int j = 0; j < 8; ++j) acc[i][j] = fmaf(xa[i], yb[j], acc[i][j]);
        }
    }
    const int col0 = n0 + tn;
#pragma unroll
    for (int i = 0; i < 8; ++i) {
        const int gm = m0 + tm + i;
        *(float4*)&OUT[(size_t)gm * 1024 + col0] = make_float4(acc[i][0], acc[i][1], acc[i][2], acc[i][3]);
        *(float4*)&OUT[(size_t)gm * 1024 + col0 + 4] = make_float4(acc[i][4], acc[i][5], acc[i][6], acc[i][7]);
    }
}

// ===================== Path B (small-ws fallback) ===========================
// Recompute k,v head-slices from x@W on the fly; phi; accumulate S,sumk.
__global__ __launch_bounds__(256) void k_kv_fused(const float* __restrict__ X,
                                                  const float* __restrict__ W,
                                                  const float* __restrict__ At,
                                                  float* __restrict__ S,
                                                  float* __restrict__ sumk) {
    const int ch = blockIdx.x, h = ch & 15, c = ch >> 4;
    const int split = blockIdx.y;
    const int tid = threadIdx.x;
    __shared__ float Xs[32][36];
    __shared__ float Ws[32][128];
    __shared__ float Krst[64][36];
    __shared__ float Vs[32][64];
    __shared__ float Kph[32][260];
    __shared__ float nks[32];
    const int row = tid >> 3, g = tid & 7;
    float Sacc[8][8] = {};
    float skacc[8] = {};
    const int tl = tid >> 6, tf = tid & 63;
    const int tf2 = tid & 31, dg = tid >> 5;
    const float* Ab = At + (size_t)h * 64 * 256;

    for (int chunk = 0; chunk < 16; ++chunk) {
        const int l0 = split * 512 + chunk * 32;
        float ak[8] = {}, av[8] = {};
        for (int kt = 0; kt < 1024; kt += 32) {
            __syncthreads();
            *(float4*)&Xs[row][g * 4] =
                *(const float4*)&X[((size_t)(c * 4096 + l0 + row)) * 1024 + kt + g * 4];
#pragma unroll
            for (int t = 0; t < 4; ++t) {
                const int task = t * 256 + tid;
                const int col = task & 127, kc4 = (task >> 7) * 4;
                const int wrow = (col < 64) ? (1024 + h * 64 + col) : (2048 + h * 64 + (col - 64));
                const float4 wv = *(const float4*)&W[(size_t)wrow * 1024 + kt + kc4];
                Ws[kc4 + 0][col] = wv.x; Ws[kc4 + 1][col] = wv.y;
                Ws[kc4 + 2][col] = wv.z; Ws[kc4 + 3][col] = wv.w;
            }
            __syncthreads();
#pragma unroll
            for (int kk = 0; kk < 32; ++kk) {
                const float xr = Xs[row][kk];
                const float4 w0 = *(const float4*)&Ws[kk][g * 8];
                const float4 w1 = *(const float4*)&Ws[kk][g * 8 + 4];
                const float4 w2 = *(const float4*)&Ws[kk][64 + g * 8];
                const float4 w3 = *(const float4*)&Ws[kk][64 + g * 8 + 4];
                const float wk[8] = {w0.x, w0.y, w0.z, w0.w, w1.x, w1.y, w1.z, w1.w};
                const float wv8[8] = {w2.x, w2.y, w2.z, w2.w, w3.x, w3.y, w3.z, w3.w};
#pragma unroll
                for (int j = 0; j < 8; ++j) {
                    ak[j] = fmaf(xr, wk[j], ak[j]);
                    av[j] = fmaf(xr, wv8[j], av[j]);
                }
            }
        }
        const int l = l0 + row;
        if (l > 0) {
            const float pos = (float)(l - 1);
#pragma unroll
            for (int p = 0; p < 4; ++p) {
                const int dd = g * 8 + 2 * p;
                const float freq = exp2f(-(float)dd * (LOG2_10000 / 64.0f));
                float sn, cs;
                sincosf(pos * freq, &sn, &cs);
                const float t1 = ak[2 * p], t2 = ak[2 * p + 1];
                ak[2 * p] = t1 * cs - t2 * sn;
                ak[2 * p + 1] = t1 * sn + t2 * cs;
            }
        }
        float ss = 0.f;
#pragma unroll
        for (int j = 0; j < 8; ++j) ss += ak[j] * ak[j];
#pragma unroll
        for (int off = 1; off < 8; off <<= 1) ss += __shfl_xor(ss, off);
        __syncthreads();
#pragma unroll
        for (int j = 0; j < 8; ++j) Krst[g * 8 + j][row] = ak[j];
        *(float4*)&Vs[row][g * 8] = make_float4(av[0], av[1], av[2], av[3]);
        *(float4*)&Vs[row][g * 8 + 4] = make_float4(av[4], av[5], av[6], av[7]);
        if (g == 0) nks[row] = ss * 0.5f;
        __syncthreads();
        // phase A
        float pacc[8][4] = {};
        for (int d = 0; d < 64; ++d) {
            const float4 avv = *(const float4*)&Ab[d * 256 + tf * 4];
            const float4 k0 = *(const float4*)&Krst[d][tl * 8];
            const float4 k1 = *(const float4*)&Krst[d][tl * 8 + 4];
            const float ka[8] = {k0.x, k0.y, k0.z, k0.w, k1.x, k1.y, k1.z, k1.w};
            const float ab4[4] = {avv.x, avv.y, avv.z, avv.w};
#pragma unroll
            for (int i = 0; i < 8; ++i)
#pragma unroll
                for (int j = 0; j < 4; ++j) pacc[i][j] = fmaf(ka[i], ab4[j], pacc[i][j]);
        }
#pragma unroll
        for (int i = 0; i < 8; ++i) {
            const float n = nks[tl * 8 + i];
            float4 kp;
            kp.x = expf(pacc[i][0] - n) * 0.0625f;
            kp.y = expf(pacc[i][1] - n) * 0.0625f;
            kp.z = expf(pacc[i][2] - n) * 0.0625f;
            kp.w = expf(pacc[i][3] - n) * 0.0625f;
            *(float4*)&Kph[tl * 8 + i][tf * 4] = kp;
        }
        __syncthreads();
        // phase B
#pragma unroll 4
        for (int l2 = 0; l2 < 32; ++l2) {
            const float4 a0 = *(const float4*)&Kph[l2][tf2 * 8];
            const float4 a1 = *(const float4*)&Kph[l2][tf2 * 8 + 4];
            const float4 b0 = *(const float4*)&Vs[l2][dg * 8];
            const float4 b1 = *(const float4*)&Vs[l2][dg * 8 + 4];
            const float fa[8] = {a0.x, a0.y, a0.z, a0.w, a1.x, a1.y, a1.z, a1.w};
            const float fb[8] = {b0.x, b0.y, b0.z, b0.w, b1.x, b1.y, b1.z, b1.w};
#pragma unroll
            for (int i = 0; i < 8; ++i)
#pragma unroll
                for (int j = 0; j < 8; ++j) Sacc[i][j] = fmaf(fa[i], fb[j], Sacc[i][j]);
            if (dg == 0) {
#pragma unroll
                for (int i = 0; i < 8; ++i) skacc[i] += fa[i];
            }
        }
    }
    float* Sb = S + (size_t)ch * 256 * 64;
#pragma unroll
    for (int i = 0; i < 8; ++i)
#pragma unroll
        for (int j = 0; j < 8; ++j)
            atomicAdd(&Sb[(size_t)(tf2 * 8 + i) * 64 + dg * 8 + j], Sacc[i][j]);
    if (dg == 0) {
#pragma unroll
        for (int i = 0; i < 8; ++i) atomicAdd(&sumk[(size_t)ch * 256 + tf2 * 8 + i], skacc[i]);
    }
}

// Recompute q, phi, numer/denom, then atomic-accumulate out contribution.
__global__ __launch_bounds__(256) void k_q_fused(const float* __restrict__ X,
                                                 const float* __restrict__ W,
                                                 const float* __restrict__ Wout,
                                                 const float* __restrict__ At,
                                                 const float* __restrict__ S,
                                                 const float* __restrict__ sumk,
                                                 float* __restrict__ OUT) {
    const int ch = blockIdx.x, h = ch & 15, c = ch >> 4;
    const int lb = blockIdx.y;
    const int l0 = lb * 32;
    const int tid = threadIdx.x;
    __shared__ float Xs[32][36];
    __shared__ float Ws[32][64];
    __shared__ float Qrst[64][36];
    __shared__ float Qph[32][260];   // reused as WoS[64][68] in phase C
    __shared__ float nqs[32];
    __shared__ float sks[256];
    __shared__ float OhS[32][68];
    const int row = tid >> 3, g = tid & 7;
    const float* Ab = At + (size_t)h * 64 * 256;
    const float* Sb = S + (size_t)ch * 256 * 64;

    sks[tid] = sumk[(size_t)ch * 256 + tid];

    float aq[8] = {};
    for (int kt = 0; kt < 1024; kt += 32) {
        __syncthreads();
        *(float4*)&Xs[row][g * 4] =
            *(const float4*)&X[((size_t)(c * 4096 + l0 + row)) * 1024 + kt + g * 4];
#pragma unroll
        for (int t = 0; t < 2; ++t) {
            const int task = t * 256 + tid;
            const int col = task & 63, kc4 = (task >> 6) * 4;
            const float4 wv = *(const float4*)&W[(size_t)(h * 64 + col) * 1024 + kt + kc4];
            Ws[kc4 + 0][col] = wv.x; Ws[kc4 + 1][col] = wv.y;
            Ws[kc4 + 2][col] = wv.z; Ws[kc4 + 3][col] = wv.w;
        }
        __syncthreads();
#pragma unroll
        for (int kk = 0; kk < 32; ++kk) {
            const float xr = Xs[row][kk];
            const float4 w0 = *(const float4*)&Ws[kk][g * 8];
            const float4 w1 = *(const float4*)&Ws[kk][g * 8 + 4];
            const float wk[8] = {w0.x, w0.y, w0.z, w0.w, w1.x, w1.y, w1.z, w1.w};
#pragma unroll
            for (int j = 0; j < 8; ++j) aq[j] = fmaf(xr, wk[j], aq[j]);
        }
    }
    const int l = l0 + row;
    if (l > 0) {
        const float pos = (float)(l - 1);
#pragma unroll
        for (int p = 0; p < 4; ++p) {
            const int dd = g * 8 + 2 * p;
            const float freq = exp2f(-(float)dd * (LOG2_10000 / 64.0f));
            float sn, cs;
            sincosf(pos * freq, &sn, &cs);
            const float t1 = aq[2 * p], t2 = aq[2 * p + 1];
            aq[2 * p] = t1 * cs - t2 * sn;
            aq[2 * p + 1] = t1 * sn + t2 * cs;
        }
    }
    float ss = 0.f;
#pragma unroll
    for (int j = 0; j < 8; ++j) ss += aq[j] * aq[j];
#pragma unroll
    for (int off = 1; off < 8; off <<= 1) ss += __shfl_xor(ss, off);
    __syncthreads();
#pragma unroll
    for (int j = 0; j < 8; ++j) Qrst[g * 8 + j][row] = aq[j];
    if (g == 0) nqs[row] = ss * 0.5f;
    __syncthreads();
    // phase A: Qph
    {
        const int tl = tid >> 6, tf = tid & 63;
        float pacc[8][4] = {};
        for (int d = 0; d < 64; ++d) {
            const float4 avv = *(const float4*)&Ab[d * 256 + tf * 4];
            const float4 k0 = *(const float4*)&Qrst[d][tl * 8];
            const float4 k1 = *(const float4*)&Qrst[d][tl * 8 + 4];
            const float ka[8] = {k0.x, k0.y, k0.z, k0.w, k1.x, k1.y, k1.z, k1.w};
            const float ab4[4] = {avv.x, avv.y, avv.z, avv.w};
#pragma unroll
            for (int i = 0; i < 8; ++i)
#pragma unroll
                for (int j = 0; j < 4; ++j) pacc[i][j] = fmaf(ka[i], ab4[j], pacc[i][j]);
        }
#pragma unroll
        for (int i = 0; i < 8; ++i) {
            const float n = nqs[tl * 8 + i];
            float4 kp;
            kp.x = expf(pacc[i][0] - n) * 0.0625f;
            kp.y = expf(pacc[i][1] - n) * 0.0625f;
            kp.z = expf(pacc[i][2] - n) * 0.0625f;
            kp.w = expf(pacc[i][3] - n) * 0.0625f;
            *(float4*)&Qph[tl * 8 + i][tf * 4] = kp;
        }
    }
    __syncthreads();
    // phase B: numer/denom -> OhS
    {
        const int dgf = tid & 7, lf = tid >> 3;
        float num[8] = {};
        float dn = 0.f;
        for (int f = 0; f < 256; ++f) {
            const float qv = Qph[lf][f];
            const float4 s0 = *(const float4*)&Sb[(size_t)f * 64 + dgf * 8];
            const float4 s1 = *(const float4*)&Sb[(size_t)f * 64 + dgf * 8 + 4];
            num[0] = fmaf(qv, s0.x, num[0]);
            num[1] = fmaf(qv, s0.y, num[1]);
            num[2] = fmaf(qv, s0.z, num[2]);
            num[3] = fmaf(qv, s0.w, num[3]);
            num[4] = fmaf(qv, s1.x, num[4]);
            num[5] = fmaf(qv, s1.y, num[5]);
            num[6] = fmaf(qv, s1.z, num[6]);
            num[7] = fmaf(qv, s1.w, num[7]);
            dn = fmaf(qv, sks[f], dn);
        }
        const float rden = 1.0f / fmaxf(dn, 1e-6f);
        *(float4*)&OhS[lf][dgf * 8] =
            make_float4(num[0] * rden, num[1] * rden, num[2] * rden, num[3] * rden);
        *(float4*)&OhS[lf][dgf * 8 + 4] =
            make_float4(num[4] * rden, num[5] * rden, num[6] * rden, num[7] * rden);
    }
    // phase C: out[l0+row][nt*64 + g*8 + j] += sum_e OhS[row][e]*Wout[n][h*64+e]
    float* WoS = &Qph[0][0];   // [64][68] view, 4352 floats <= 8320
    for (int nt = 0; nt < 16; ++nt) {
        __syncthreads();
#pragma unroll
        for (int t = 0; t < 4; ++t) {
            const int task = t * 256 + tid;
            const int colw = task >> 4;
            const int e4 = (task & 15) * 4;
            *(float4*)&WoS[colw * 68 + e4] =
                *(const float4*)&Wout[(size_t)(nt * 64 + colw) * 1024 + h * 64 + e4];
        }
        __syncthreads();
        float acc8[8] = {};
        for (int e4 = 0; e4 < 16; ++e4) {
            const float4 o4 = *(const float4*)&OhS[row][e4 * 4];
#pragma unroll
            for (int j = 0; j < 8; ++j) {
                const float4 w4 = *(const float4*)&WoS[(g * 8 + j) * 68 + e4 * 4];
                acc8[j] = fmaf(o4.x, w4.x, acc8[j]);
                acc8[j] = fmaf(o4.y, w4.y, acc8[j]);
                acc8[j] = fmaf(o4.z, w4.z, acc8[j]);
                acc8[j] = fmaf(o4.w, w4.w, acc8[j]);
            }
        }
        const size_t ob = ((size_t)(c * 4096 + l0 + row)) * 1024 + nt * 64 + g * 8;
#pragma unroll
        for (int j = 0; j < 8; ++j) atomicAdd(&OUT[ob + j], acc8[j]);
    }
}

// ------------------------- launcher ----------------------------------------
extern "C" void kernel_launch(void* const* d_in, const int* in_sizes, int n_in,
                              void* d_out, int out_size, void* d_ws, size_t ws_size,
                              hipStream_t stream) {
    const float* x      = (const float*)d_in[0];
    const float* w_qkv  = (const float*)d_in[1];
    const float* w_out  = (const float*)d_in[2];
    const float* signs  = (const float*)d_in[3];
    const float* scales = (const float*)d_in[4];
    float* out = (float*)d_out;
    float* ws = (float*)d_ws;

    const size_t NQK = (size_t)4 * 16 * 4096 * 64;   // 16,777,216
    const size_t S_ELEMS  = (size_t)64 * 256 * 64;   // 1,048,576
    const size_t SK_ELEMS = (size_t)64 * 256;        // 16,384
    const size_t N_ELEMS  = (size_t)64 * 4096;       // 262,144
    const size_t AT_ELEMS = (size_t)16 * 64 * 256;   // 262,144
    const size_t needA = (2 * NQK + S_ELEMS + SK_ELEMS + 2 * N_ELEMS + AT_ELEMS) * sizeof(float);

    if (ws_size >= needA) {
        float* buf1 = ws;              // kr, later qr
        float* buf2 = buf1 + NQK;      // vv, later oh
        float* S    = buf2 + NQK;
        float* sumk = S + S_ELEMS;
        float* nq   = sumk + SK_ELEMS;
        float* nk   = nq + N_ELEMS;
        float* At   = nk + N_ELEMS;
        k_zero<<<dim3(2048), dim3(256), 0, stream>>>(S, S_ELEMS + SK_ELEMS + 2 * N_ELEMS);
        k_build_at<<<dim3(64), dim3(64), 0, stream>>>(signs, scales, At);
        // pass 1: K,V (cols 1024..3071)
        k_qkv<<<dim3(16, 128), dim3(256), 0, stream>>>(x, w_qkv, buf1, buf1, buf2, nq, nk, 1024);
        k_kvstats<<<dim3(64, 8), dim3(256), 0, stream>>>(buf1, buf2, nk, At, S, sumk);
        // pass 2: Q (cols 0..1023), overwrites kr
        k_qkv<<<dim3(8, 128), dim3(256), 0, stream>>>(x, w_qkv, buf1, buf1, buf2, nq, nk, 0);
        k_attn<<<dim3(64, 128), dim3(256), 0, stream>>>(buf1, nq, At, S, sumk, buf2);
        k_outgemm<<<dim3(8, 128), dim3(256), 0, stream>>>(buf2, w_out, out);
    } else {
        // minimal-ws fallback: ~5.3 MB
        float* S    = ws;
        float* sumk = S + S_ELEMS;
        float* At   = sumk + SK_ELEMS;
        k_zero<<<dim3(1024), dim3(256), 0, stream>>>(S, S_ELEMS + SK_ELEMS);
        k_zero<<<dim3(2048), dim3(256), 0, stream>>>(out, (size_t)out_size);
        k_build_at<<<dim3(64), dim3(64), 0, stream>>>(signs, scales, At);
        k_kv_fused<<<dim3(64, 8), dim3(256), 0, stream>>>(x, w_qkv, At, S, sumk);
        k_q_fused<<<dim3(64, 128), dim3(256), 0, stream>>>(x, w_qkv, w_out, At, S, sumk, out);
    }
}

// Round 3
// 882.879 us; speedup vs baseline: 2.9061x; 2.9061x over previous
//
#include <hip/hip_runtime.h>
#include <math.h>

// ---------------------------------------------------------------------------
// FastAttention (Performer/SORF linear attention) — MFMA bf16 pipeline.
//  k_cvt_w      : w_qkv -> whi/wlo (split bf16), w_out -> wob (bf16)
//  k_build_atf  : SORF matrix Atf[h][f=256][d=64] bf16
//  k_zero       : zero St, sumk
//  k_qkv_mfma   : qkv = x@w^T via split-bf16 MFMA (3 products) + RoPE +
//                 norms(from rounded bf16!) -> qb/kb/vb bf16 (C,H,L,D), nq/nk
//  k_kvstats    : phi_k^T = Atf·K^T (MFMA, swapped), exp, St[d][f] += V^T·P^T,
//                 sumk (atomics over 8 L-splits)
//  k_cvt_st     : St fp32 + sumk -> Stb bf16 [ch][80][256] (row64=sumk)
//  k_attn       : phi_q (MFMA), exp, numer/denom = phi_q @ Stb^T (80 cols),
//                 oh = numer/max(denom,eps) -> bf16
//  k_outgemm    : out = oh @ wob^T (bf16 MFMA, fp32 out)
// ---------------------------------------------------------------------------

#define LOG2_10000 13.287712379549449f

typedef __attribute__((ext_vector_type(8))) short short8v;
typedef __attribute__((ext_vector_type(4))) float f32x4;

static __device__ __forceinline__ unsigned short f2bf(float f) {
    unsigned u = __float_as_uint(f);
    u = (u + 0x7fffu + ((u >> 16) & 1u)) >> 16;
    return (unsigned short)u;
}
static __device__ __forceinline__ float bf2f(unsigned short h) {
    return __uint_as_float((unsigned)h << 16);
}

#define GLDS16(gptr, lptr) __builtin_amdgcn_global_load_lds( \
    (const __attribute__((address_space(1))) void*)(gptr),   \
    (__attribute__((address_space(3))) void*)(lptr), 16, 0, 0)

// ------------------------- zero ------------------------------------------
__global__ __launch_bounds__(256) void k_zero(float* __restrict__ p, size_t n) {
    size_t i = (size_t)blockIdx.x * 256 + threadIdx.x;
    const size_t st = (size_t)gridDim.x * 256;
    for (; i < n; i += st) p[i] = 0.0f;
}

// ------------------------- convert weights -------------------------------
__global__ __launch_bounds__(256) void k_cvt_w(const float* __restrict__ wqkv,
                                               const float* __restrict__ wout,
                                               unsigned short* __restrict__ whi,
                                               unsigned short* __restrict__ wlo,
                                               unsigned short* __restrict__ wob) {
    const size_t n1 = (size_t)3072 * 1024 / 4, n2 = (size_t)1024 * 1024 / 4;
    const size_t st = (size_t)gridDim.x * 256;
    for (size_t i = (size_t)blockIdx.x * 256 + threadIdx.x; i < n1; i += st) {
        float4 v = ((const float4*)wqkv)[i];
        float vv[4] = {v.x, v.y, v.z, v.w};
        ushort4 h, l;
        unsigned short hh[4], ll[4];
#pragma unroll
        for (int j = 0; j < 4; ++j) { hh[j] = f2bf(vv[j]); ll[j] = f2bf(vv[j] - bf2f(hh[j])); }
        h.x = hh[0]; h.y = hh[1]; h.z = hh[2]; h.w = hh[3];
        l.x = ll[0]; l.y = ll[1]; l.z = ll[2]; l.w = ll[3];
        ((ushort4*)whi)[i] = h;
        ((ushort4*)wlo)[i] = l;
    }
    for (size_t i = (size_t)blockIdx.x * 256 + threadIdx.x; i < n2; i += st) {
        float4 v = ((const float4*)wout)[i];
        ushort4 h;
        h.x = f2bf(v.x); h.y = f2bf(v.y); h.z = f2bf(v.z); h.w = f2bf(v.w);
        ((ushort4*)wob)[i] = h;
    }
}

// ------------------------- build Atf bf16 [h][f=256][d=64] ----------------
__global__ __launch_bounds__(64) void k_build_atf(const float* __restrict__ signs,
                                                  const float* __restrict__ scales,
                                                  unsigned short* __restrict__ atfG) {
    const int b = blockIdx.x;          // h*4 + r
    const int hh = b >> 2, r = b & 3;
    const int j = threadIdx.x;         // input dim d
    const float* s1 = signs + ((size_t)(hh * 4 + r) * 3 + 0) * 64;
    const float* s2 = s1 + 64;
    const float* s3 = s1 + 128;
    const float* sc = scales + (size_t)(hh * 4 + r) * 64;

    float v[64];
    const float s1j = s1[j];
#pragma unroll
    for (int p = 0; p < 64; ++p) v[p] = (p == j) ? s1j : 0.0f;
#pragma unroll
    for (int st = 1; st < 64; st <<= 1)
#pragma unroll
        for (int p = 0; p < 64; ++p)
            if (!(p & st)) { float a = v[p], bq = v[p | st]; v[p] = a + bq; v[p | st] = a - bq; }
#pragma unroll
    for (int p = 0; p < 64; ++p) v[p] *= s2[p];
#pragma unroll
    for (int st = 1; st < 64; st <<= 1)
#pragma unroll
        for (int p = 0; p < 64; ++p)
            if (!(p & st)) { float a = v[p], bq = v[p | st]; v[p] = a + bq; v[p | st] = a - bq; }
#pragma unroll
    for (int p = 0; p < 64; ++p) v[p] *= s3[p];
#pragma unroll
    for (int st = 1; st < 64; st <<= 1)
#pragma unroll
        for (int p = 0; p < 64; ++p)
            if (!(p & st)) { float a = v[p], bq = v[p | st]; v[p] = a + bq; v[p | st] = a - bq; }
#pragma unroll
    for (int p = 0; p < 64; ++p)
        atfG[((size_t)hh * 256 + r * 64 + p) * 64 + j] = f2bf(v[p] * sc[p] * (1.0f / 4096.0f));
}

// ------------------------- QKV split-bf16 MFMA GEMM -----------------------
// C[m][n] = sum_k X[m][k] * W[n][k];  M=16384, N=3072, K=1024.
// grid (24 bn, 128 bm), 256 thr (4 waves, 2x2), 128x128 tile, BK=64.
__global__ __launch_bounds__(256) void k_qkv_mfma(const float* __restrict__ X,
                                                  const unsigned short* __restrict__ whi,
                                                  const unsigned short* __restrict__ wlo,
                                                  unsigned short* __restrict__ qb,
                                                  unsigned short* __restrict__ kb,
                                                  unsigned short* __restrict__ vb,
                                                  float* __restrict__ nq,
                                                  float* __restrict__ nk) {
    __shared__ char smem[65536];
    unsigned short* Ah = (unsigned short*)smem;          // 16KB: [8 ks][128 row][8]
    unsigned short* Al = Ah + 8192;
    unsigned short* Bh = Al + 8192;
    unsigned short* Bl = Bh + 8192;
    unsigned short* Ol = (unsigned short*)smem;          // epilogue overlay [128][136]

    const int tid = threadIdx.x;
    const int lane = tid & 63, w = tid >> 6;
    const int wm = w >> 1, wn = w & 1;
    const int bn = blockIdx.x, bm = blockIdx.y;
    const int m0 = bm * 128, n0 = bn * 128;

    f32x4 acc[4][4];
    const f32x4 zz = {0.f, 0.f, 0.f, 0.f};
#pragma unroll
    for (int i = 0; i < 4; ++i)
#pragma unroll
        for (int j = 0; j < 4; ++j) acc[i][j] = zz;

    for (int kt = 0; kt < 1024; kt += 64) {
        __syncthreads();
        // B tiles via global_load_lds (bf16 hi/lo)
#pragma unroll
        for (int j = 0; j < 4; ++j) {
            const int g = (w * 4 + j) * 64 + lane;
            const int row = g & 127, ks = g >> 7;
            GLDS16(whi + (size_t)(n0 + row) * 1024 + kt + ks * 8, Bh + g * 8);
            GLDS16(wlo + (size_t)(n0 + row) * 1024 + kt + ks * 8, Bl + g * 8);
        }
        // A tile: fp32 -> hi/lo bf16 via registers
#pragma unroll
        for (int g4 = 0; g4 < 4; ++g4) {
            const int g = tid * 4 + g4;
            const int row = g & 127, ks = g >> 7;
            const float* src = X + (size_t)(m0 + row) * 1024 + kt + ks * 8;
            const float4 x0 = *(const float4*)src;
            const float4 x1 = *(const float4*)(src + 4);
            const float xv[8] = {x0.x, x0.y, x0.z, x0.w, x1.x, x1.y, x1.z, x1.w};
            short8v H, L;
#pragma unroll
            for (int j = 0; j < 8; ++j) {
                unsigned short hh = f2bf(xv[j]);
                H[j] = (short)hh;
                L[j] = (short)f2bf(xv[j] - bf2f(hh));
            }
            *(short8v*)(Ah + g * 8) = H;
            *(short8v*)(Al + g * 8) = L;
        }
        __syncthreads();
#pragma unroll
        for (int s = 0; s < 2; ++s) {
            const int kd = s * 4 + (lane >> 4);
            short8v ah[4], al[4], bh[4], bl[4];
#pragma unroll
            for (int i = 0; i < 4; ++i) {
                const int off = (kd * 128 + wm * 64 + i * 16 + (lane & 15)) * 8;
                ah[i] = *(short8v*)(Ah + off);
                al[i] = *(short8v*)(Al + off);
            }
#pragma unroll
            for (int j = 0; j < 4; ++j) {
                const int off = (kd * 128 + wn * 64 + j * 16 + (lane & 15)) * 8;
                bh[j] = *(short8v*)(Bh + off);
                bl[j] = *(short8v*)(Bl + off);
            }
#pragma unroll
            for (int i = 0; i < 4; ++i)
#pragma unroll
                for (int j = 0; j < 4; ++j) {
                    acc[i][j] = __builtin_amdgcn_mfma_f32_16x16x32_bf16(ah[i], bh[j], acc[i][j], 0, 0, 0);
                    acc[i][j] = __builtin_amdgcn_mfma_f32_16x16x32_bf16(ah[i], bl[j], acc[i][j], 0, 0, 0);
                    acc[i][j] = __builtin_amdgcn_mfma_f32_16x16x32_bf16(al[i], bh[j], acc[i][j], 0, 0, 0);
                }
        }
    }

    // epilogue: RoPE (fp32) -> round bf16 -> norms from rounded -> store
    __syncthreads();   // all waves done reading LDS; safe to overlay Ol

    const int sec = n0 >> 10;  // 0=q 1=k 2=v (block-uniform)
    float freqj[4];
#pragma unroll
    for (int j = 0; j < 4; ++j) {
        const int colw = wn * 64 + j * 16 + (lane & 15);
        const int dd_even = (colw & 63) & ~1;
        freqj[j] = exp2f(-(float)dd_even * (LOG2_10000 / 64.0f));
    }

#pragma unroll
    for (int i = 0; i < 4; ++i) {
        float nsum[4] = {0.f, 0.f, 0.f, 0.f};
#pragma unroll
        for (int j = 0; j < 4; ++j) {
            const int colw = wn * 64 + j * 16 + (lane & 15);
#pragma unroll
            for (int r = 0; r < 4; ++r) {
                float v = acc[i][j][r];
                const float partner = __shfl_xor(v, 1);
                const int gm = m0 + wm * 64 + i * 16 + (lane >> 4) * 4 + r;
                const int l = gm & 4095;
                if (sec < 2 && l > 0) {
                    float sn, cs;
                    sincosf((float)(l - 1) * freqj[j], &sn, &cs);
                    v = v * cs + sn * ((lane & 1) ? partner : -partner);
                }
                const unsigned short hv = f2bf(v);
                if (sec < 2) {
                    const float vb_ = bf2f(hv);
                    nsum[r] += vb_ * vb_;
                }
                Ol[(wm * 64 + i * 16 + (lane >> 4) * 4 + r) * 136 + colw] = hv;
            }
        }
        if (sec < 2) {
#pragma unroll
            for (int m = 1; m < 16; m <<= 1)
#pragma unroll
                for (int r = 0; r < 4; ++r) nsum[r] += __shfl_xor(nsum[r], m);
            if ((lane & 15) == 0) {
                float* ntgt = (sec == 0) ? nq : nk;
                const int hh = ((unsigned)(n0 + wn * 64) >> 6) & 15;
#pragma unroll
                for (int r = 0; r < 4; ++r) {
                    const int gm = m0 + wm * 64 + i * 16 + (lane >> 4) * 4 + r;
                    const int c = gm >> 12, l = gm & 4095;
                    ntgt[((size_t)(c * 16 + hh)) * 4096 + l] = 0.5f * nsum[r];
                }
            }
        }
    }
    __syncthreads();
    // coalesced copy-out
    {
        const int row = tid >> 1, half = tid & 1;
        const int gm = m0 + row;
        const int c = gm >> 12, l = gm & 4095;
        const int hh = ((unsigned)(n0 + half * 64) >> 6) & 15;
        unsigned short* tgt = (sec == 0) ? qb : (sec == 1) ? kb : vb;
        const size_t base = ((size_t)(c * 16 + hh) * 4096 + l) * 64;
#pragma unroll
        for (int q8 = 0; q8 < 8; ++q8)
            *(short8v*)(tgt + base + q8 * 8) = *(short8v*)(Ol + row * 136 + half * 64 + q8 * 8);
    }
}

// ------------------------- kvstats: St[d][f], sumk ------------------------
// grid (64 ch, 8 split), 256 thr (4 waves). Chunks of 32 l.
__global__ __launch_bounds__(256) void k_kvstats(const unsigned short* __restrict__ kb,
                                                 const unsigned short* __restrict__ vb,
                                                 const float* __restrict__ nkG,
                                                 const unsigned short* __restrict__ atfG,
                                                 float* __restrict__ St,
                                                 float* __restrict__ sumk) {
    __shared__ char smem[4096 + 5120 + 20480 + 128];
    unsigned short* kl = (unsigned short*)smem;              // [8 ks][32 l][8]
    unsigned short* vt = kl + 2048;                          // [64 d][40]
    unsigned short* pt = vt + 2560;                          // [256 f][40]
    float* nks = (float*)(pt + 10240);                       // [32]

    const int tid = threadIdx.x;
    const int lane = tid & 63, w = tid >> 6;
    const int ch = blockIdx.x, split = blockIdx.y;
    const int h = ch & 15;
    const unsigned short* atfH = atfG + (size_t)h * 16384;

    f32x4 Sacc[4][4];
    const f32x4 zz = {0.f, 0.f, 0.f, 0.f};
#pragma unroll
    for (int i = 0; i < 4; ++i)
#pragma unroll
        for (int j = 0; j < 4; ++j) Sacc[i][j] = zz;
    float skr[4][4] = {};

    for (int chunk = 0; chunk < 16; ++chunk) {
        const int l0 = split * 512 + chunk * 32;
        __syncthreads();
        // stage K chunk via global_load_lds
        {
            const int g = w * 64 + lane;   // 256 granules
            GLDS16(kb + ((size_t)ch * 4096 + l0 + (g & 31)) * 64 + (g >> 5) * 8, kl + g * 8);
        }
        // stage V transposed (reg)
        {
            const int l = tid >> 3, d0 = (tid & 7) * 8;
            const short8v vv = *(const short8v*)(vb + ((size_t)ch * 4096 + l0 + l) * 64 + d0);
#pragma unroll
            for (int j = 0; j < 8; ++j) vt[(d0 + j) * 40 + l] = (unsigned short)vv[j];
        }
        if (tid < 32) nks[tid] = nkG[(size_t)ch * 4096 + l0 + tid];
        __syncthreads();
        // phi^T MFMA: C[f][l] = sum_d Atf[f][d] * K[l][d]
        f32x4 p[4][2];
#pragma unroll
        for (int i = 0; i < 4; ++i) { p[i][0] = zz; p[i][1] = zz; }
#pragma unroll
        for (int ks = 0; ks < 2; ++ks) {
            const int kd = ks * 4 + (lane >> 4);
            short8v bfr[2];
#pragma unroll
            for (int nf = 0; nf < 2; ++nf)
                bfr[nf] = *(short8v*)(kl + (kd * 32 + nf * 16 + (lane & 15)) * 8);
#pragma unroll
            for (int mf = 0; mf < 4; ++mf) {
                const int f = w * 64 + mf * 16 + (lane & 15);
                const short8v a = *(const short8v*)(atfH + (size_t)f * 64 + kd * 8);
#pragma unroll
                for (int nf = 0; nf < 2; ++nf)
                    p[mf][nf] = __builtin_amdgcn_mfma_f32_16x16x32_bf16(a, bfr[nf], p[mf][nf], 0, 0, 0);
            }
        }
        // exp, write Pt, accumulate sumk partials
#pragma unroll
        for (int mf = 0; mf < 4; ++mf)
#pragma unroll
            for (int nf = 0; nf < 2; ++nf) {
                const int ll = nf * 16 + (lane & 15);
                const float nv = nks[ll];
#pragma unroll
                for (int r = 0; r < 4; ++r) {
                    const float e = expf(p[mf][nf][r] - nv) * 0.0625f;
                    skr[mf][r] += e;
                    const int fr = w * 64 + mf * 16 + (lane >> 4) * 4 + r;
                    pt[fr * 40 + ll] = f2bf(e);
                }
            }
        __syncthreads();
        // St MFMA: C[d][f] = sum_l Vt[d][l] * Pt[f][l]
        short8v bfr2[4];
#pragma unroll
        for (int nf = 0; nf < 4; ++nf)
            bfr2[nf] = *(short8v*)(pt + (w * 64 + nf * 16 + (lane & 15)) * 40 + (lane >> 4) * 8);
#pragma unroll
        for (int mf = 0; mf < 4; ++mf) {
            const short8v a = *(short8v*)(vt + (mf * 16 + (lane & 15)) * 40 + (lane >> 4) * 8);
#pragma unroll
            for (int nf = 0; nf < 4; ++nf)
                Sacc[mf][nf] = __builtin_amdgcn_mfma_f32_16x16x32_bf16(a, bfr2[nf], Sacc[mf][nf], 0, 0, 0);
        }
    }
    // commit
#pragma unroll
    for (int mf = 0; mf < 4; ++mf)
#pragma unroll
        for (int nf = 0; nf < 4; ++nf)
#pragma unroll
            for (int r = 0; r < 4; ++r) {
                const int d = mf * 16 + (lane >> 4) * 4 + r;
                const int f = w * 64 + nf * 16 + (lane & 15);
                atomicAdd(&St[((size_t)ch * 64 + d) * 256 + f], Sacc[mf][nf][r]);
            }
#pragma unroll
    for (int mf = 0; mf < 4; ++mf) {
#pragma unroll
        for (int m = 1; m < 16; m <<= 1)
#pragma unroll
            for (int r = 0; r < 4; ++r) skr[mf][r] += __shfl_xor(skr[mf][r], m);
        if ((lane & 15) == 0)
#pragma unroll
            for (int r = 0; r < 4; ++r)
                atomicAdd(&sumk[(size_t)ch * 256 + w * 64 + mf * 16 + (lane >> 4) * 4 + r], skr[mf][r]);
    }
}

// ------------------------- St fp32 -> Stb bf16 [ch][80][256] --------------
__global__ __launch_bounds__(256) void k_cvt_st(const float* __restrict__ St,
                                                const float* __restrict__ sumk,
                                                unsigned short* __restrict__ Stb) {
    const size_t n = (size_t)64 * 80 * 256;
    const size_t st = (size_t)gridDim.x * 256;
    for (size_t e = (size_t)blockIdx.x * 256 + threadIdx.x; e < n; e += st) {
        const int f = (int)(e & 255);
        const int row = (int)((e >> 8) % 80);
        const int ch = (int)(e / (80 * 256));
        float v = 0.0f;
        if (row < 64) v = St[((size_t)ch * 64 + row) * 256 + f];
        else if (row == 64) v = sumk[(size_t)ch * 256 + f];
        Stb[e] = f2bf(v);
    }
}

// ------------------------- attn: oh = (phi_q @ S) / denom -----------------
// grid (64 ch, 64 lblocks of 64), 256 thr (4 waves).
__global__ __launch_bounds__(256) void k_attn(const unsigned short* __restrict__ qb,
                                              const float* __restrict__ nqG,
                                              const unsigned short* __restrict__ atfG,
                                              const unsigned short* __restrict__ Stb,
                                              unsigned short* __restrict__ oh) {
    __shared__ char smem[32768 + 8192 + 256];
    unsigned short* pq = (unsigned short*)smem;        // [32 ks][64 l][8]
    unsigned short* ql = pq + 16384;                   // [8 ks][64 l][8]
    float* nqs = (float*)(ql + 4096);                  // [64]
    unsigned short* olds = pq;                         // overlay [64][72]

    const int tid = threadIdx.x;
    const int lane = tid & 63, w = tid >> 6;
    const int ch = blockIdx.x, lb = blockIdx.y;
    const int h = ch & 15, c = ch >> 4;
    const int l0 = lb * 64;
    const unsigned short* atfH = atfG + (size_t)h * 16384;
    const unsigned short* stbH = Stb + (size_t)ch * 20480;

    // stage Q (512 granules) + nq
#pragma unroll
    for (int j = 0; j < 2; ++j) {
        const int g = (w * 2 + j) * 64 + lane;
        GLDS16(qb + ((size_t)ch * 4096 + l0 + (g & 63)) * 64 + (g >> 6) * 8, ql + g * 8);
    }
    if (tid < 64) nqs[tid] = nqG[(size_t)ch * 4096 + l0 + tid];
    __syncthreads();

    const f32x4 zz = {0.f, 0.f, 0.f, 0.f};
    // phi_q: C[l][f] = sum_d Q[l][d] * Atf[f][d]; wave w owns l-range w*16.
    {
        f32x4 p[16];
#pragma unroll
        for (int nf = 0; nf < 16; ++nf) p[nf] = zz;
#pragma unroll
        for (int ks = 0; ks < 2; ++ks) {
            const int kd = ks * 4 + (lane >> 4);
            const short8v a = *(short8v*)(ql + (kd * 64 + w * 16 + (lane & 15)) * 8);
#pragma unroll
            for (int nf = 0; nf < 16; ++nf) {
                const int f = nf * 16 + (lane & 15);
                const short8v b = *(const short8v*)(atfH + (size_t)f * 64 + kd * 8);
                p[nf] = __builtin_amdgcn_mfma_f32_16x16x32_bf16(a, b, p[nf], 0, 0, 0);
            }
        }
        float nv[4];
#pragma unroll
        for (int r = 0; r < 4; ++r) nv[r] = nqs[w * 16 + (lane >> 4) * 4 + r];
#pragma unroll
        for (int nf = 0; nf < 16; ++nf) {
            const int f = nf * 16 + (lane & 15);
#pragma unroll
            for (int r = 0; r < 4; ++r) {
                const float e = expf(p[nf][r] - nv[r]) * 0.0625f;
                const int l = w * 16 + (lane >> 4) * 4 + r;
                pq[((f >> 3) * 64 + l) * 8 + (f & 7)] = f2bf(e);
            }
        }
    }
    __syncthreads();
    // numer/denom: C[l][dd<80] = sum_f Pq[l][f] * Stb[dd][f]
    f32x4 nacc[5];
#pragma unroll
    for (int nf = 0; nf < 5; ++nf) nacc[nf] = zz;
#pragma unroll
    for (int ks = 0; ks < 8; ++ks) {
        const int kd = ks * 4 + (lane >> 4);
        const short8v a = *(short8v*)(pq + (kd * 64 + w * 16 + (lane & 15)) * 8);
#pragma unroll
        for (int nf = 0; nf < 5; ++nf) {
            const int dd = nf * 16 + (lane & 15);
            const short8v b = *(const short8v*)(stbH + (size_t)dd * 256 + kd * 8);
            nacc[nf] = __builtin_amdgcn_mfma_f32_16x16x32_bf16(a, b, nacc[nf], 0, 0, 0);
        }
    }
    __syncthreads();   // pq reads done everywhere; safe to overlay olds
    {
#pragma unroll
        for (int r = 0; r < 4; ++r) {
            const float dn = __shfl(nacc[4][r], (lane & 48));
            const float rden = 1.0f / fmaxf(dn, 1e-6f);
            const int row = w * 16 + (lane >> 4) * 4 + r;
#pragma unroll
            for (int nf = 0; nf < 4; ++nf)
                olds[row * 72 + nf * 16 + (lane & 15)] = f2bf(nacc[nf][r] * rden);
        }
    }
    __syncthreads();
    {
        const int row = tid >> 2, d0 = (tid & 3) * 16;
        const size_t base = ((size_t)c * 4096 + l0 + row) * 1024 + h * 64 + d0;
        *(short8v*)(oh + base) = *(short8v*)(olds + row * 72 + d0);
        *(short8v*)(oh + base + 8) = *(short8v*)(olds + row * 72 + d0 + 8);
    }
}

// ------------------------- out = oh @ wob^T (bf16 MFMA) -------------------
// grid (8 bn, 128 bm), 256 thr, 128x128 tile, BK=64.
__global__ __launch_bounds__(256) void k_outgemm(const unsigned short* __restrict__ OH,
                                                 const unsigned short* __restrict__ WOB,
                                                 float* __restrict__ OUT) {
    __shared__ char smem[32768];
    unsigned short* Asm = (unsigned short*)smem;   // 16KB [8 ks][128][8]
    unsigned short* Bsm = Asm + 8192;

    const int tid = threadIdx.x;
    const int lane = tid & 63, w = tid >> 6;
    const int wm = w >> 1, wn = w & 1;
    const int m0 = blockIdx.y * 128, n0 = blockIdx.x * 128;

    f32x4 acc[4][4];
    const f32x4 zz = {0.f, 0.f, 0.f, 0.f};
#pragma unroll
    for (int i = 0; i < 4; ++i)
#pragma unroll
        for (int j = 0; j < 4; ++j) acc[i][j] = zz;

    for (int kt = 0; kt < 1024; kt += 64) {
        __syncthreads();
#pragma unroll
        for (int j = 0; j < 4; ++j) {
            const int g = (w * 4 + j) * 64 + lane;
            const int row = g & 127, ks = g >> 7;
            GLDS16(OH + (size_t)(m0 + row) * 1024 + kt + ks * 8, Asm + g * 8);
            GLDS16(WOB + (size_t)(n0 + row) * 1024 + kt + ks * 8, Bsm + g * 8);
        }
        __syncthreads();
#pragma unroll
        for (int s = 0; s < 2; ++s) {
            const int kd = s * 4 + (lane >> 4);
            short8v af[4], bf[4];
#pragma unroll
            for (int i = 0; i < 4; ++i)
                af[i] = *(short8v*)(Asm + (kd * 128 + wm * 64 + i * 16 + (lane & 15)) * 8);
#pragma unroll
            for (int j = 0; j < 4; ++j)
                bf[j] = *(short8v*)(Bsm + (kd * 128 + wn * 64 + j * 16 + (lane & 15)) * 8);
#pragma unroll
            for (int i = 0; i < 4; ++i)
#pragma unroll
                for (int j = 0; j < 4; ++j)
                    acc[i][j] = __builtin_amdgcn_mfma_f32_16x16x32_bf16(af[i], bf[j], acc[i][j], 0, 0, 0);
        }
    }
#pragma unroll
    for (int i = 0; i < 4; ++i)
#pragma unroll
        for (int j = 0; j < 4; ++j)
#pragma unroll
            for (int r = 0; r < 4; ++r) {
                const int gm = m0 + wm * 64 + i * 16 + (lane >> 4) * 4 + r;
                const int gn = n0 + wn * 64 + j * 16 + (lane & 15);
                OUT[(size_t)gm * 1024 + gn] = acc[i][j][r];
            }
}

// ------------------------- launcher ----------------------------------------
extern "C" void kernel_launch(void* const* d_in, const int* in_sizes, int n_in,
                              void* d_out, int out_size, void* d_ws, size_t ws_size,
                              hipStream_t stream) {
    const float* x      = (const float*)d_in[0];
    const float* w_qkv  = (const float*)d_in[1];
    const float* w_out  = (const float*)d_in[2];
    const float* signs  = (const float*)d_in[3];
    const float* scales = (const float*)d_in[4];
    float* out = (float*)d_out;

    unsigned short* us = (unsigned short*)d_ws;
    unsigned short* qb  = us;                      // 16,777,216
    unsigned short* kb  = qb + 16777216;           // 16,777,216  (oh overlays)
    unsigned short* vb  = kb + 16777216;           // 16,777,216
    unsigned short* whi = vb + 16777216;           // 3,145,728
    unsigned short* wlo = whi + 3145728;           // 3,145,728
    unsigned short* wob = wlo + 3145728;           // 1,048,576
    unsigned short* atf = wob + 1048576;           // 262,144
    unsigned short* stb = atf + 262144;            // 1,310,720
    float* St   = (float*)(stb + 1310720);         // 1,048,576
    float* sumk = St + 1048576;                    // 16,384
    float* nq   = sumk + 16384;                    // 262,144
    float* nk   = nq + 262144;                     // 262,144
    unsigned short* oh = kb;                       // overlay (kb dead after kvstats)

    k_cvt_w<<<dim3(1024), dim3(256), 0, stream>>>(w_qkv, w_out, whi, wlo, wob);
    k_build_atf<<<dim3(64), dim3(64), 0, stream>>>(signs, scales, atf);
    k_zero<<<dim3(1024), dim3(256), 0, stream>>>(St, (size_t)1048576 + 16384);
    k_qkv_mfma<<<dim3(24, 128), dim3(256), 0, stream>>>(x, whi, wlo, qb, kb, vb, nq, nk);
    k_kvstats<<<dim3(64, 8), dim3(256), 0, stream>>>(kb, vb, nk, atf, St, sumk);
    k_cvt_st<<<dim3(1280), dim3(256), 0, stream>>>(St, sumk, stb);
    k_attn<<<dim3(64, 64), dim3(256), 0, stream>>>(qb, nq, atf, stb, oh);
    k_outgemm<<<dim3(8, 128), dim3(256), 0, stream>>>(oh, wob, out);
}

// Round 6
// 721.566 us; speedup vs baseline: 3.5558x; 1.2236x over previous
//
#include <hip/hip_runtime.h>
#include <math.h>

// ---------------------------------------------------------------------------
// FastAttention (Performer/SORF linear attention) — fp16 MFMA pipeline.
//   k_cvt_xw   : x->xh fp16, w_qkv->wh fp16, w_out->wob fp16
//   k_build_atf: SORF matrix Atf[h][f=256][d=64] fp16
//   k_qkv_f16  : qkv = x@w^T (fp16 MFMA, K=1024) + RoPE + norms(from rounded
//                fp16) -> kb/vb (pass1) / qb=kb-slot (pass2), nq/nk fp32
//   k_minred   : M[ch] = min_l nk
//   k_kvstats  : kphi' = exp(A k - nk + M) (fp16), St[d][f] += V^T P^T, sumk
//   k_cvt_st   : Stb fp16 [ch][80][256] = sigma * (St ; sumk ; 0-pad)
//   k_attn     : qphi' = exp(A q) fp16; numer/denom = qphi' @ Stb^T;
//                oh = numer / max(denom, exp(nq+M-15.2018)) -> fp16
//   k_outgemm  : out = oh @ wob^T (fp16 MFMA, fp32 out)
// Scaling algebra: numer' = sigma*256*e^{M+nq} * numer_ref, so the clamp
// threshold is sigma*256*1e-6*e^{M+nq} = exp(M+nq+ln(2.5e-7)); ratio == ref.
// ---------------------------------------------------------------------------

#define LOG2_10000 13.287712379549449f
#define TCONST 15.201805f   // -ln(1e-6 * 256 * 2^-10)
#define SIGMA 0.0009765625f // 2^-10

typedef __attribute__((ext_vector_type(8))) _Float16 h8;
typedef __attribute__((ext_vector_type(4))) _Float16 h4;
typedef __attribute__((ext_vector_type(4))) float f32x4;

#define GLDS16(gptr, lptr) __builtin_amdgcn_global_load_lds( \
    (const __attribute__((address_space(1))) void*)(gptr),   \
    (__attribute__((address_space(3))) void*)(lptr), 16, 0, 0)

// ------------------------- zero ------------------------------------------
__global__ __launch_bounds__(256) void k_zero(float* __restrict__ p, size_t n) {
    size_t i = (size_t)blockIdx.x * 256 + threadIdx.x;
    const size_t st = (size_t)gridDim.x * 256;
    for (; i < n; i += st) p[i] = 0.0f;
}

// ------------------------- convert inputs to fp16 -------------------------
__global__ __launch_bounds__(256) void k_cvt_xw(const float* __restrict__ x,
                                                const float* __restrict__ wqkv,
                                                const float* __restrict__ wout,
                                                _Float16* __restrict__ xh,
                                                _Float16* __restrict__ wh,
                                                _Float16* __restrict__ wob) {
    const size_t st = (size_t)gridDim.x * 256;
    const size_t nx = (size_t)16384 * 1024 / 4;
    for (size_t i = (size_t)blockIdx.x * 256 + threadIdx.x; i < nx; i += st) {
        float4 v = ((const float4*)x)[i];
        h4 o = {(_Float16)v.x, (_Float16)v.y, (_Float16)v.z, (_Float16)v.w};
        ((h4*)xh)[i] = o;
    }
    const size_t nw = (size_t)3072 * 1024 / 4;
    for (size_t i = (size_t)blockIdx.x * 256 + threadIdx.x; i < nw; i += st) {
        float4 v = ((const float4*)wqkv)[i];
        h4 o = {(_Float16)v.x, (_Float16)v.y, (_Float16)v.z, (_Float16)v.w};
        ((h4*)wh)[i] = o;
    }
    const size_t no = (size_t)1024 * 1024 / 4;
    for (size_t i = (size_t)blockIdx.x * 256 + threadIdx.x; i < no; i += st) {
        float4 v = ((const float4*)wout)[i];
        h4 o = {(_Float16)v.x, (_Float16)v.y, (_Float16)v.z, (_Float16)v.w};
        ((h4*)wob)[i] = o;
    }
}

// ------------------------- build Atf fp16 [h][f=256][d=64] ----------------
__global__ __launch_bounds__(64) void k_build_atf(const float* __restrict__ signs,
                                                  const float* __restrict__ scales,
                                                  _Float16* __restrict__ atfG) {
    const int b = blockIdx.x;          // h*4 + r
    const int hh = b >> 2, r = b & 3;
    const int j = threadIdx.x;         // input dim d
    const float* s1 = signs + ((size_t)(hh * 4 + r) * 3 + 0) * 64;
    const float* s2 = s1 + 64;
    const float* s3 = s1 + 128;
    const float* sc = scales + (size_t)(hh * 4 + r) * 64;

    float v[64];
    const float s1j = s1[j];
#pragma unroll
    for (int p = 0; p < 64; ++p) v[p] = (p == j) ? s1j : 0.0f;
#pragma unroll
    for (int st = 1; st < 64; st <<= 1)
#pragma unroll
        for (int p = 0; p < 64; ++p)
            if (!(p & st)) { float a = v[p], bq = v[p | st]; v[p] = a + bq; v[p | st] = a - bq; }
#pragma unroll
    for (int p = 0; p < 64; ++p) v[p] *= s2[p];
#pragma unroll
    for (int st = 1; st < 64; st <<= 1)
#pragma unroll
        for (int p = 0; p < 64; ++p)
            if (!(p & st)) { float a = v[p], bq = v[p | st]; v[p] = a + bq; v[p | st] = a - bq; }
#pragma unroll
    for (int p = 0; p < 64; ++p) v[p] *= s3[p];
#pragma unroll
    for (int st = 1; st < 64; st <<= 1)
#pragma unroll
        for (int p = 0; p < 64; ++p)
            if (!(p & st)) { float a = v[p], bq = v[p | st]; v[p] = a + bq; v[p | st] = a - bq; }
#pragma unroll
    for (int p = 0; p < 64; ++p)
        atfG[((size_t)hh * 256 + r * 64 + p) * 64 + j] = (_Float16)(v[p] * sc[p] * (1.0f / 4096.0f));
}

// ------------------------- QKV fp16 MFMA GEMM -----------------------------
// C[m][n] = sum_k X[m][k]*W[n][k]; M=16384, K=1024. 128x128 tile, BK=64.
__global__ __launch_bounds__(256) void k_qkv_f16(const _Float16* __restrict__ xh,
                                                 const _Float16* __restrict__ wh,
                                                 _Float16* __restrict__ qb,
                                                 _Float16* __restrict__ kb,
                                                 _Float16* __restrict__ vb,
                                                 float* __restrict__ nq,
                                                 float* __restrict__ nk,
                                                 int n_base) {
    __shared__ char smem[34816];
    _Float16* Ah = (_Float16*)smem;          // [8 ks][128 row][8]
    _Float16* Bh = Ah + 8192;
    _Float16* Ol = (_Float16*)smem;          // epilogue overlay [128][136]

    const int tid = threadIdx.x;
    const int lane = tid & 63, w = tid >> 6;
    const int lane16 = lane & 15, lrow = lane >> 4;
    const int wm = w >> 1, wn = w & 1;
    const int m0 = blockIdx.y * 128, n0 = n_base + blockIdx.x * 128;

    f32x4 acc[4][4];
    const f32x4 zz = {0.f, 0.f, 0.f, 0.f};
#pragma unroll
    for (int i = 0; i < 4; ++i)
#pragma unroll
        for (int j = 0; j < 4; ++j) acc[i][j] = zz;

    for (int kt = 0; kt < 1024; kt += 64) {
        __syncthreads();
#pragma unroll
        for (int j = 0; j < 4; ++j) {
            const int g = (w * 4 + j) * 64 + lane;
            const int row = g & 127, ks = g >> 7;
            GLDS16(xh + (size_t)(m0 + row) * 1024 + kt + ks * 8, Ah + g * 8);
            GLDS16(wh + (size_t)(n0 + row) * 1024 + kt + ks * 8, Bh + g * 8);
        }
        __syncthreads();
#pragma unroll
        for (int s = 0; s < 2; ++s) {
            const int kd = s * 4 + lrow;
            h8 af[4], bf[4];
#pragma unroll
            for (int i = 0; i < 4; ++i)
                af[i] = *(h8*)(Ah + (kd * 128 + wm * 64 + i * 16 + lane16) * 8);
#pragma unroll
            for (int j = 0; j < 4; ++j)
                bf[j] = *(h8*)(Bh + (kd * 128 + wn * 64 + j * 16 + lane16) * 8);
#pragma unroll
            for (int i = 0; i < 4; ++i)
#pragma unroll
                for (int j = 0; j < 4; ++j)
                    acc[i][j] = __builtin_amdgcn_mfma_f32_16x16x32_f16(af[i], bf[j], acc[i][j], 0, 0, 0);
        }
    }

    // epilogue: RoPE (fp32) -> round fp16 -> norms from rounded -> store
    __syncthreads();
    const int sec = n0 >> 10;  // 0=q 1=k 2=v (block-uniform)
    float freqj[4];
#pragma unroll
    for (int j = 0; j < 4; ++j) {
        const int colw = wn * 64 + j * 16 + lane16;
        freqj[j] = exp2f(-(float)((colw & 63) & ~1) * (LOG2_10000 / 64.0f));
    }

#pragma unroll
    for (int i = 0; i < 4; ++i) {
        float nsum[4] = {0.f, 0.f, 0.f, 0.f};
#pragma unroll
        for (int j = 0; j < 4; ++j) {
            const int colw = wn * 64 + j * 16 + lane16;
#pragma unroll
            for (int r = 0; r < 4; ++r) {
                float v = acc[i][j][r];
                const float partner = __shfl_xor(v, 1);
                const int gm = m0 + wm * 64 + i * 16 + lrow * 4 + r;
                const int l = gm & 4095;
                if (sec < 2 && l > 0) {
                    float sn, cs;
                    sincosf((float)(l - 1) * freqj[j], &sn, &cs);
                    v = v * cs + sn * ((lane & 1) ? partner : -partner);
                }
                const _Float16 hv = (_Float16)v;
                if (sec < 2) {
                    const float vr = (float)hv;
                    nsum[r] += vr * vr;
                }
                Ol[(wm * 64 + i * 16 + lrow * 4 + r) * 136 + colw] = hv;
            }
        }
        if (sec < 2) {
#pragma unroll
            for (int m = 1; m < 16; m <<= 1)
#pragma unroll
                for (int r = 0; r < 4; ++r) nsum[r] += __shfl_xor(nsum[r], m);
            if (lane16 == 0) {
                float* ntgt = (sec == 0) ? nq : nk;
                const int hh = ((unsigned)(n0 + wn * 64) >> 6) & 15;
#pragma unroll
                for (int r = 0; r < 4; ++r) {
                    const int gm = m0 + wm * 64 + i * 16 + lrow * 4 + r;
                    const int c = gm >> 12, l = gm & 4095;
                    ntgt[((size_t)(c * 16 + hh)) * 4096 + l] = 0.5f * nsum[r];
                }
            }
        }
    }
    __syncthreads();
    // coalesced copy-out to (C,H,L,64)
    {
        const int row = tid >> 1, half = tid & 1;
        const int gm = m0 + row;
        const int c = gm >> 12, l = gm & 4095;
        const int hh = ((unsigned)(n0 + half * 64) >> 6) & 15;
        _Float16* tgt = (sec == 0) ? qb : (sec == 1) ? kb : vb;
        const size_t base = ((size_t)(c * 16 + hh) * 4096 + l) * 64;
#pragma unroll
        for (int q8 = 0; q8 < 8; ++q8)
            *(h8*)(tgt + base + q8 * 8) = *(h8*)(Ol + row * 136 + half * 64 + q8 * 8);
    }
}

// ------------------------- M[ch] = min_l nk -------------------------------
__global__ __launch_bounds__(256) void k_minred(const float* __restrict__ nk,
                                                float* __restrict__ MG) {
    const int ch = blockIdx.x;
    const int tid = threadIdx.x;
    __shared__ float red[4];
    float v = 1e30f;
    for (int i = tid; i < 4096; i += 256) v = fminf(v, nk[(size_t)ch * 4096 + i]);
#pragma unroll
    for (int off = 32; off >= 1; off >>= 1) v = fminf(v, __shfl_down(v, off));
    if ((tid & 63) == 0) red[tid >> 6] = v;
    __syncthreads();
    if (tid == 0) MG[ch] = fminf(fminf(red[0], red[1]), fminf(red[2], red[3]));
}

// ------------------------- kvstats: St[d][f], sumk ------------------------
__global__ __launch_bounds__(256) void k_kvstats(const _Float16* __restrict__ kb,
                                                 const _Float16* __restrict__ vb,
                                                 const float* __restrict__ nkG,
                                                 const _Float16* __restrict__ atfG,
                                                 const float* __restrict__ MG,
                                                 float* __restrict__ St,
                                                 float* __restrict__ sumk) {
    __shared__ char smem[29824];
    _Float16* kl = (_Float16*)smem;              // [8 ks][32 l][8]
    _Float16* vt = kl + 2048;                    // [64 d][40]
    _Float16* pt = vt + 2560;                    // [256 f][40]
    float* nks = (float*)(pt + 10240);           // [32]

    const int tid = threadIdx.x;
    const int lane = tid & 63, w = tid >> 6;
    const int lane16 = lane & 15, lrow = lane >> 4;
    const int ch = blockIdx.x, split = blockIdx.y;
    const int h = ch & 15;
    const _Float16* atfH = atfG + (size_t)h * 16384;
    const float Mch = MG[ch];

    f32x4 Sacc[4][4];
    const f32x4 zz = {0.f, 0.f, 0.f, 0.f};
#pragma unroll
    for (int i = 0; i < 4; ++i)
#pragma unroll
        for (int j = 0; j < 4; ++j) Sacc[i][j] = zz;
    float skr[4][4] = {};

    for (int chunk = 0; chunk < 16; ++chunk) {
        const int l0 = split * 512 + chunk * 32;
        __syncthreads();
        {
            const int g = w * 64 + lane;
            GLDS16(kb + ((size_t)ch * 4096 + l0 + (g & 31)) * 64 + (g >> 5) * 8, kl + g * 8);
        }
        {
            const int l = tid >> 3, d0 = (tid & 7) * 8;
            const h8 vv = *(const h8*)(vb + ((size_t)ch * 4096 + l0 + l) * 64 + d0);
#pragma unroll
            for (int j = 0; j < 8; ++j) vt[(d0 + j) * 40 + l] = vv[j];
        }
        if (tid < 32) nks[tid] = nkG[(size_t)ch * 4096 + l0 + tid];
        __syncthreads();
        // phi^T: C[f][l] = sum_d Atf[f][d]*K[l][d]
        f32x4 p[4][2];
#pragma unroll
        for (int i = 0; i < 4; ++i) { p[i][0] = zz; p[i][1] = zz; }
#pragma unroll
        for (int ks = 0; ks < 2; ++ks) {
            const int kd = ks * 4 + lrow;
            h8 bfr[2];
#pragma unroll
            for (int nf = 0; nf < 2; ++nf)
                bfr[nf] = *(h8*)(kl + (kd * 32 + nf * 16 + lane16) * 8);
#pragma unroll
            for (int mf = 0; mf < 4; ++mf) {
                const int f = w * 64 + mf * 16 + lane16;
                const h8 a = *(const h8*)(atfH + (size_t)f * 64 + kd * 8);
#pragma unroll
                for (int nf = 0; nf < 2; ++nf)
                    p[mf][nf] = __builtin_amdgcn_mfma_f32_16x16x32_f16(a, bfr[nf], p[mf][nf], 0, 0, 0);
            }
        }
#pragma unroll
        for (int mf = 0; mf < 4; ++mf)
#pragma unroll
            for (int nf = 0; nf < 2; ++nf) {
                const int ll = nf * 16 + lane16;
                const float nv = nks[ll];
#pragma unroll
                for (int r = 0; r < 4; ++r) {
                    const float e = expf(p[mf][nf][r] - nv + Mch);
                    skr[mf][r] += e;
                    const int fr = w * 64 + mf * 16 + lrow * 4 + r;
                    pt[fr * 40 + ll] = (_Float16)e;
                }
            }
        __syncthreads();
        // St: C[d][f] = sum_l Vt[d][l]*Pt[f][l]
        h8 bfr2[4];
#pragma unroll
        for (int nf = 0; nf < 4; ++nf)
            bfr2[nf] = *(h8*)(pt + (w * 64 + nf * 16 + lane16) * 40 + lrow * 8);
#pragma unroll
        for (int mf = 0; mf < 4; ++mf) {
            const h8 a = *(h8*)(vt + (mf * 16 + lane16) * 40 + lrow * 8);
#pragma unroll
            for (int nf = 0; nf < 4; ++nf)
                Sacc[mf][nf] = __builtin_amdgcn_mfma_f32_16x16x32_f16(a, bfr2[nf], Sacc[mf][nf], 0, 0, 0);
        }
    }
#pragma unroll
    for (int mf = 0; mf < 4; ++mf)
#pragma unroll
        for (int nf = 0; nf < 4; ++nf)
#pragma unroll
            for (int r = 0; r < 4; ++r) {
                const int d = mf * 16 + lrow * 4 + r;
                const int f = w * 64 + nf * 16 + lane16;
                atomicAdd(&St[((size_t)ch * 64 + d) * 256 + f], Sacc[mf][nf][r]);
            }
#pragma unroll
    for (int mf = 0; mf < 4; ++mf) {
#pragma unroll
        for (int m = 1; m < 16; m <<= 1)
#pragma unroll
            for (int r = 0; r < 4; ++r) skr[mf][r] += __shfl_xor(skr[mf][r], m);
        if (lane16 == 0)
#pragma unroll
            for (int r = 0; r < 4; ++r)
                atomicAdd(&sumk[(size_t)ch * 256 + w * 64 + mf * 16 + lrow * 4 + r], skr[mf][r]);
    }
}

// ------------------------- St fp32 -> Stb fp16 [ch][80][256] --------------
__global__ __launch_bounds__(256) void k_cvt_st(const float* __restrict__ St,
                                                const float* __restrict__ sumk,
                                                _Float16* __restrict__ Stb) {
    const size_t n = (size_t)64 * 80 * 256;
    const size_t st = (size_t)gridDim.x * 256;
    for (size_t e = (size_t)blockIdx.x * 256 + threadIdx.x; e < n; e += st) {
        const int f = (int)(e & 255);
        const int row = (int)((e >> 8) % 80);
        const int ch = (int)(e / (80 * 256));
        float v = 0.0f;
        if (row < 64) v = St[((size_t)ch * 64 + row) * 256 + f];
        else if (row == 64) v = sumk[(size_t)ch * 256 + f];
        Stb[e] = (_Float16)(v * SIGMA);
    }
}

// ------------------------- attn: oh = numer / max(denom, T) ---------------
__global__ __launch_bounds__(256) void k_attn(const _Float16* __restrict__ qb,
                                              const float* __restrict__ nqG,
                                              const _Float16* __restrict__ atfG,
                                              const _Float16* __restrict__ Stb,
                                              const float* __restrict__ MG,
                                              _Float16* __restrict__ oh) {
    __shared__ char smem[41216];
    _Float16* pq = (_Float16*)smem;              // [32 ks][64 l][8]
    _Float16* ql = pq + 16384;                   // [8 ks][64 l][8]
    float* nqs = (float*)(ql + 4096);            // [64]
    _Float16* olds = pq;                         // overlay [64][72]

    const int tid = threadIdx.x;
    const int lane = tid & 63, w = tid >> 6;
    const int lane16 = lane & 15, lrow = lane >> 4;
    const int ch = blockIdx.x, lb = blockIdx.y;
    const int h = ch & 15, c = ch >> 4;
    const int l0 = lb * 64;
    const _Float16* atfH = atfG + (size_t)h * 16384;
    const _Float16* stbH = Stb + (size_t)ch * 20480;
    const float Mch = MG[ch];

#pragma unroll
    for (int j = 0; j < 2; ++j) {
        const int g = (w * 2 + j) * 64 + lane;
        GLDS16(qb + ((size_t)ch * 4096 + l0 + (g & 63)) * 64 + (g >> 6) * 8, ql + g * 8);
    }
    if (tid < 64) nqs[tid] = nqG[(size_t)ch * 4096 + l0 + tid];
    __syncthreads();

    const f32x4 zz = {0.f, 0.f, 0.f, 0.f};
    // phi_q: C[l][f] = sum_d Q[l][d]*Atf[f][d]; wave w owns rows w*16..+16
    {
        f32x4 p[16];
#pragma unroll
        for (int nf = 0; nf < 16; ++nf) p[nf] = zz;
#pragma unroll
        for (int ks = 0; ks < 2; ++ks) {
            const int kd = ks * 4 + lrow;
            const h8 a = *(h8*)(ql + (kd * 64 + w * 16 + lane16) * 8);
#pragma unroll
            for (int nf = 0; nf < 16; ++nf) {
                const int f = nf * 16 + lane16;
                const h8 b = *(const h8*)(atfH + (size_t)f * 64 + kd * 8);
                p[nf] = __builtin_amdgcn_mfma_f32_16x16x32_f16(a, b, p[nf], 0, 0, 0);
            }
        }
#pragma unroll
        for (int nf = 0; nf < 16; ++nf) {
            const int f = nf * 16 + lane16;
#pragma unroll
            for (int r = 0; r < 4; ++r) {
                const float e = expf(p[nf][r]);   // no norm subtract (folded into T)
                const int l = w * 16 + lrow * 4 + r;
                pq[((f >> 3) * 64 + l) * 8 + (f & 7)] = (_Float16)e;
            }
        }
    }
    __syncthreads();
    // numer/denom: C[l][dd<80] = sum_f Pq[l][f]*Stb[dd][f]
    f32x4 nacc[5];
#pragma unroll
    for (int nf = 0; nf < 5; ++nf) nacc[nf] = zz;
#pragma unroll
    for (int ks = 0; ks < 8; ++ks) {
        const int kd = ks * 4 + lrow;
        const h8 a = *(h8*)(pq + (kd * 64 + w * 16 + lane16) * 8);
#pragma unroll
        for (int nf = 0; nf < 5; ++nf) {
            const int dd = nf * 16 + lane16;
            const h8 b = *(const h8*)(stbH + (size_t)dd * 256 + kd * 8);
            nacc[nf] = __builtin_amdgcn_mfma_f32_16x16x32_f16(a, b, nacc[nf], 0, 0, 0);
        }
    }
    __syncthreads();
    {
#pragma unroll
        for (int r = 0; r < 4; ++r) {
            const float dn = __shfl(nacc[4][r], (lane & 48));  // dd==64 col
            const int row = w * 16 + lrow * 4 + r;
            const float t = expf(nqs[row] + Mch - TCONST);
            const float rden = 1.0f / fmaxf(dn, t);
#pragma unroll
            for (int nf = 0; nf < 4; ++nf)
                olds[row * 72 + nf * 16 + lane16] = (_Float16)(nacc[nf][r] * rden);
        }
    }
    __syncthreads();
    {
        const int row = tid >> 2, d0 = (tid & 3) * 16;
        const size_t base = ((size_t)c * 4096 + l0 + row) * 1024 + h * 64 + d0;
        *(h8*)(oh + base) = *(h8*)(olds + row * 72 + d0);
        *(h8*)(oh + base + 8) = *(h8*)(olds + row * 72 + d0 + 8);
    }
}

// ------------------------- out = oh @ wob^T (fp16 MFMA) -------------------
__global__ __launch_bounds__(256) void k_outgemm(const _Float16* __restrict__ OH,
                                                 const _Float16* __restrict__ WOB,
                                                 float* __restrict__ OUT) {
    __shared__ char smem[32768];
    _Float16* Asm = (_Float16*)smem;   // [8 ks][128][8]
    _Float16* Bsm = Asm + 8192;

    const int tid = threadIdx.x;
    const int lane = tid & 63, w = tid >> 6;
    const int lane16 = lane & 15, lrow = lane >> 4;
    const int wm = w >> 1, wn = w & 1;
    const int m0 = blockIdx.y * 128, n0 = blockIdx.x * 128;

    f32x4 acc[4][4];
    const f32x4 zz = {0.f, 0.f, 0.f, 0.f};
#pragma unroll
    for (int i = 0; i < 4; ++i)
#pragma unroll
        for (int j = 0; j < 4; ++j) acc[i][j] = zz;

    for (int kt = 0; kt < 1024; kt += 64) {
        __syncthreads();
#pragma unroll
        for (int j = 0; j < 4; ++j) {
            const int g = (w * 4 + j) * 64 + lane;
            const int row = g & 127, ks = g >> 7;
            GLDS16(OH + (size_t)(m0 + row) * 1024 + kt + ks * 8, Asm + g * 8);
            GLDS16(WOB + (size_t)(n0 + row) * 1024 + kt + ks * 8, Bsm + g * 8);
        }
        __syncthreads();
#pragma unroll
        for (int s = 0; s < 2; ++s) {
            const int kd = s * 4 + lrow;
            h8 af[4], bf[4];
#pragma unroll
            for (int i = 0; i < 4; ++i)
                af[i] = *(h8*)(Asm + (kd * 128 + wm * 64 + i * 16 + lane16) * 8);
#pragma unroll
            for (int j = 0; j < 4; ++j)
                bf[j] = *(h8*)(Bsm + (kd * 128 + wn * 64 + j * 16 + lane16) * 8);
#pragma unroll
            for (int i = 0; i < 4; ++i)
#pragma unroll
                for (int j = 0; j < 4; ++j)
                    acc[i][j] = __builtin_amdgcn_mfma_f32_16x16x32_f16(af[i], bf[j], acc[i][j], 0, 0, 0);
        }
    }
#pragma unroll
    for (int i = 0; i < 4; ++i)
#pragma unroll
        for (int j = 0; j < 4; ++j)
#pragma unroll
            for (int r = 0; r < 4; ++r) {
                const int gm = m0 + wm * 64 + i * 16 + lrow * 4 + r;
                const int gn = n0 + wn * 64 + j * 16 + lane16;
                OUT[(size_t)gm * 1024 + gn] = acc[i][j][r];
            }
}

// ------------------------- launcher ----------------------------------------
extern "C" void kernel_launch(void* const* d_in, const int* in_sizes, int n_in,
                              void* d_out, int out_size, void* d_ws, size_t ws_size,
                              hipStream_t stream) {
    const float* x      = (const float*)d_in[0];
    const float* w_qkv  = (const float*)d_in[1];
    const float* w_out  = (const float*)d_in[2];
    const float* signs  = (const float*)d_in[3];
    const float* scales = (const float*)d_in[4];
    float* out = (float*)d_out;

    _Float16* hs = (_Float16*)d_ws;
    _Float16* xh  = hs;                       // 16,777,216
    _Float16* wh  = xh + 16777216;            // 3,145,728
    _Float16* wob = wh + 3145728;             // 1,048,576
    _Float16* kb  = wob + 1048576;            // 16,777,216  (qb overlays)
    _Float16* vb  = kb + 16777216;            // 16,777,216  (oh overlays)
    _Float16* atf = vb + 16777216;            // 262,144
    _Float16* stb = atf + 262144;             // 1,310,720
    float* St   = (float*)(stb + 1310720);    // 1,048,576
    float* sumk = St + 1048576;               // 16,384
    float* nq   = sumk + 16384;               // 262,144
    float* nk   = nq + 262144;                // 262,144
    float* MG   = nk + 262144;                // 64
    _Float16* qb = kb;                        // overlay (kb dead after kvstats)
    _Float16* oh = vb;                        // overlay (vb dead after kvstats)

    k_cvt_xw<<<dim3(1024), dim3(256), 0, stream>>>(x, w_qkv, w_out, xh, wh, wob);
    k_build_atf<<<dim3(64), dim3(64), 0, stream>>>(signs, scales, atf);
    k_zero<<<dim3(1024), dim3(256), 0, stream>>>(St, (size_t)1048576 + 16384);
    // pass 1: K,V (cols 1024..3071)
    k_qkv_f16<<<dim3(16, 128), dim3(256), 0, stream>>>(xh, wh, qb, kb, vb, nq, nk, 1024);
    k_minred<<<dim3(64), dim3(256), 0, stream>>>(nk, MG);
    k_kvstats<<<dim3(64, 8), dim3(256), 0, stream>>>(kb, vb, nk, atf, MG, St, sumk);
    k_cvt_st<<<dim3(1280), dim3(256), 0, stream>>>(St, sumk, stb);
    // pass 2: Q (cols 0..1023), overwrites kb
    k_qkv_f16<<<dim3(8, 128), dim3(256), 0, stream>>>(xh, wh, qb, kb, vb, nq, nk, 0);
    k_attn<<<dim3(64, 64), dim3(256), 0, stream>>>(qb, nq, atf, stb, MG, oh);
    k_outgemm<<<dim3(8, 128), dim3(256), 0, stream>>>(oh, wob, out);
}

// Round 7
// 709.335 us; speedup vs baseline: 3.6172x; 1.0172x over previous
//
#include <hip/hip_runtime.h>
#include <math.h>

// ---------------------------------------------------------------------------
// FastAttention (Performer/SORF linear attention) — fp16 MFMA pipeline, R7:
// GEMMs (k_qkv_f16, k_outgemm) converted to 2-phase double-buffered LDS with
// a single barrier per K-step (loads issued BEFORE compute; the __syncthreads
// vmcnt drain lands after compute) + bijective XCD-chunked block swizzle.
// kvstats/attn/cvt kernels byte-identical to R6 (isolate the change).
// ---------------------------------------------------------------------------

#define LOG2_10000 13.287712379549449f
#define TCONST 15.201805f   // -ln(1e-6 * 256 * 2^-10)
#define SIGMA 0.0009765625f // 2^-10

typedef __attribute__((ext_vector_type(8))) _Float16 h8;
typedef __attribute__((ext_vector_type(4))) _Float16 h4;
typedef __attribute__((ext_vector_type(4))) float f32x4;

#define GLDS16(gptr, lptr) __builtin_amdgcn_global_load_lds( \
    (const __attribute__((address_space(1))) void*)(gptr),   \
    (__attribute__((address_space(3))) void*)(lptr), 16, 0, 0)

// ------------------------- zero ------------------------------------------
__global__ __launch_bounds__(256) void k_zero(float* __restrict__ p, size_t n) {
    size_t i = (size_t)blockIdx.x * 256 + threadIdx.x;
    const size_t st = (size_t)gridDim.x * 256;
    for (; i < n; i += st) p[i] = 0.0f;
}

// ------------------------- convert inputs to fp16 -------------------------
__global__ __launch_bounds__(256) void k_cvt_xw(const float* __restrict__ x,
                                                const float* __restrict__ wqkv,
                                                const float* __restrict__ wout,
                                                _Float16* __restrict__ xh,
                                                _Float16* __restrict__ wh,
                                                _Float16* __restrict__ wob) {
    const size_t st = (size_t)gridDim.x * 256;
    const size_t nx = (size_t)16384 * 1024 / 4;
    for (size_t i = (size_t)blockIdx.x * 256 + threadIdx.x; i < nx; i += st) {
        float4 v = ((const float4*)x)[i];
        h4 o = {(_Float16)v.x, (_Float16)v.y, (_Float16)v.z, (_Float16)v.w};
        ((h4*)xh)[i] = o;
    }
    const size_t nw = (size_t)3072 * 1024 / 4;
    for (size_t i = (size_t)blockIdx.x * 256 + threadIdx.x; i < nw; i += st) {
        float4 v = ((const float4*)wqkv)[i];
        h4 o = {(_Float16)v.x, (_Float16)v.y, (_Float16)v.z, (_Float16)v.w};
        ((h4*)wh)[i] = o;
    }
    const size_t no = (size_t)1024 * 1024 / 4;
    for (size_t i = (size_t)blockIdx.x * 256 + threadIdx.x; i < no; i += st) {
        float4 v = ((const float4*)wout)[i];
        h4 o = {(_Float16)v.x, (_Float16)v.y, (_Float16)v.z, (_Float16)v.w};
        ((h4*)wob)[i] = o;
    }
}

// ------------------------- build Atf fp16 [h][f=256][d=64] ----------------
__global__ __launch_bounds__(64) void k_build_atf(const float* __restrict__ signs,
                                                  const float* __restrict__ scales,
                                                  _Float16* __restrict__ atfG) {
    const int b = blockIdx.x;          // h*4 + r
    const int hh = b >> 2, r = b & 3;
    const int j = threadIdx.x;         // input dim d
    const float* s1 = signs + ((size_t)(hh * 4 + r) * 3 + 0) * 64;
    const float* s2 = s1 + 64;
    const float* s3 = s1 + 128;
    const float* sc = scales + (size_t)(hh * 4 + r) * 64;

    float v[64];
    const float s1j = s1[j];
#pragma unroll
    for (int p = 0; p < 64; ++p) v[p] = (p == j) ? s1j : 0.0f;
#pragma unroll
    for (int st = 1; st < 64; st <<= 1)
#pragma unroll
        for (int p = 0; p < 64; ++p)
            if (!(p & st)) { float a = v[p], bq = v[p | st]; v[p] = a + bq; v[p | st] = a - bq; }
#pragma unroll
    for (int p = 0; p < 64; ++p) v[p] *= s2[p];
#pragma unroll
    for (int st = 1; st < 64; st <<= 1)
#pragma unroll
        for (int p = 0; p < 64; ++p)
            if (!(p & st)) { float a = v[p], bq = v[p | st]; v[p] = a + bq; v[p | st] = a - bq; }
#pragma unroll
    for (int p = 0; p < 64; ++p) v[p] *= s3[p];
#pragma unroll
    for (int st = 1; st < 64; st <<= 1)
#pragma unroll
        for (int p = 0; p < 64; ++p)
            if (!(p & st)) { float a = v[p], bq = v[p | st]; v[p] = a + bq; v[p | st] = a - bq; }
#pragma unroll
    for (int p = 0; p < 64; ++p)
        atfG[((size_t)hh * 256 + r * 64 + p) * 64 + j] = (_Float16)(v[p] * sc[p] * (1.0f / 4096.0f));
}

// ------------------------- QKV fp16 MFMA GEMM (2-phase dbuf) --------------
// C[m][n] = sum_k X[m][k]*W[n][k]; M=16384, K=1024. 128x128 tile, BK=64.
// 1D grid with bijective XCD-chunk swizzle; nbn = N-tiles.
__global__ __launch_bounds__(256) void k_qkv_f16(const _Float16* __restrict__ xh,
                                                 const _Float16* __restrict__ wh,
                                                 _Float16* __restrict__ qb,
                                                 _Float16* __restrict__ kb,
                                                 _Float16* __restrict__ vb,
                                                 float* __restrict__ nq,
                                                 float* __restrict__ nk,
                                                 int n_base, int nbn) {
    __shared__ char smem[65536];
    // dbuf layout (element offsets): A[cur] at cur*8192, B[cur] at 16384+cur*8192
    _Float16* Ol = (_Float16*)smem;          // epilogue overlay [128][136]

    const int tid = threadIdx.x;
    const int lane = tid & 63, w = tid >> 6;
    const int lane16 = lane & 15, lrow = lane >> 4;
    const int wm = w >> 1, wn = w & 1;

    // XCD-chunked swizzle (gridDim.x % 8 == 0 guaranteed by launcher)
    const int per = gridDim.x >> 3;
    const int sw = ((int)blockIdx.x & 7) * per + ((int)blockIdx.x >> 3);
    const int bn = sw % nbn, bm = sw / nbn;
    const int m0 = bm * 128, n0 = n_base + bn * 128;

    f32x4 acc[4][4];
    const f32x4 zz = {0.f, 0.f, 0.f, 0.f};
#pragma unroll
    for (int i = 0; i < 4; ++i)
#pragma unroll
        for (int j = 0; j < 4; ++j) acc[i][j] = zz;

    // prologue: stage tile 0 into buf 0
    {
        _Float16* Ad = (_Float16*)smem;
        _Float16* Bd = (_Float16*)smem + 16384;
#pragma unroll
        for (int s = 0; s < 4; ++s) {
            const int g = s * 256 + tid;
            const int row = g & 127, ks = g >> 7;
            GLDS16(xh + (size_t)(m0 + row) * 1024 + ks * 8, Ad + g * 8);
            GLDS16(wh + (size_t)(n0 + row) * 1024 + ks * 8, Bd + g * 8);
        }
    }
    __syncthreads();

    int cur = 0;
    for (int it = 0; it < 16; ++it) {
        // issue next tile's loads BEFORE compute (latency hides under MFMA)
        if (it < 15) {
            const int kt = (it + 1) * 64;
            _Float16* Ad = (_Float16*)smem + (cur ^ 1) * 8192;
            _Float16* Bd = (_Float16*)smem + 16384 + (cur ^ 1) * 8192;
#pragma unroll
            for (int s = 0; s < 4; ++s) {
                const int g = s * 256 + tid;
                const int row = g & 127, ks = g >> 7;
                GLDS16(xh + (size_t)(m0 + row) * 1024 + kt + ks * 8, Ad + g * 8);
                GLDS16(wh + (size_t)(n0 + row) * 1024 + kt + ks * 8, Bd + g * 8);
            }
        }
        const _Float16* Ah = (_Float16*)smem + cur * 8192;
        const _Float16* Bh = (_Float16*)smem + 16384 + cur * 8192;
#pragma unroll
        for (int s = 0; s < 2; ++s) {
            const int kd = s * 4 + lrow;
            h8 af[4], bf[4];
#pragma unroll
            for (int i = 0; i < 4; ++i)
                af[i] = *(const h8*)(Ah + (kd * 128 + wm * 64 + i * 16 + lane16) * 8);
#pragma unroll
            for (int j = 0; j < 4; ++j)
                bf[j] = *(const h8*)(Bh + (kd * 128 + wn * 64 + j * 16 + lane16) * 8);
#pragma unroll
            for (int i = 0; i < 4; ++i)
#pragma unroll
                for (int j = 0; j < 4; ++j)
                    acc[i][j] = __builtin_amdgcn_mfma_f32_16x16x32_f16(af[i], bf[j], acc[i][j], 0, 0, 0);
        }
        __syncthreads();   // drains lgkm (my reads done) + vmcnt (next tile landed)
        cur ^= 1;
    }

    // epilogue: RoPE (fp32) -> round fp16 -> norms from rounded -> store
    const int sec = n0 >> 10;  // 0=q 1=k 2=v (block-uniform)
    float freqj[4];
#pragma unroll
    for (int j = 0; j < 4; ++j) {
        const int colw = wn * 64 + j * 16 + lane16;
        freqj[j] = exp2f(-(float)((colw & 63) & ~1) * (LOG2_10000 / 64.0f));
    }

#pragma unroll
    for (int i = 0; i < 4; ++i) {
        float nsum[4] = {0.f, 0.f, 0.f, 0.f};
#pragma unroll
        for (int j = 0; j < 4; ++j) {
            const int colw = wn * 64 + j * 16 + lane16;
#pragma unroll
            for (int r = 0; r < 4; ++r) {
                float v = acc[i][j][r];
                const float partner = __shfl_xor(v, 1);
                const int gm = m0 + wm * 64 + i * 16 + lrow * 4 + r;
                const int l = gm & 4095;
                if (sec < 2 && l > 0) {
                    float sn, cs;
                    sincosf((float)(l - 1) * freqj[j], &sn, &cs);
                    v = v * cs + sn * ((lane & 1) ? partner : -partner);
                }
                const _Float16 hv = (_Float16)v;
                if (sec < 2) {
                    const float vr = (float)hv;
                    nsum[r] += vr * vr;
                }
                Ol[(wm * 64 + i * 16 + lrow * 4 + r) * 136 + colw] = hv;
            }
        }
        if (sec < 2) {
#pragma unroll
            for (int m = 1; m < 16; m <<= 1)
#pragma unroll
                for (int r = 0; r < 4; ++r) nsum[r] += __shfl_xor(nsum[r], m);
            if (lane16 == 0) {
                float* ntgt = (sec == 0) ? nq : nk;
                const int hh = ((unsigned)(n0 + wn * 64) >> 6) & 15;
#pragma unroll
                for (int r = 0; r < 4; ++r) {
                    const int gm = m0 + wm * 64 + i * 16 + lrow * 4 + r;
                    const int c = gm >> 12, l = gm & 4095;
                    ntgt[((size_t)(c * 16 + hh)) * 4096 + l] = 0.5f * nsum[r];
                }
            }
        }
    }
    __syncthreads();
    // coalesced copy-out to (C,H,L,64)
    {
        const int row = tid >> 1, half = tid & 1;
        const int gm = m0 + row;
        const int c = gm >> 12, l = gm & 4095;
        const int hh = ((unsigned)(n0 + half * 64) >> 6) & 15;
        _Float16* tgt = (sec == 0) ? qb : (sec == 1) ? kb : vb;
        const size_t base = ((size_t)(c * 16 + hh) * 4096 + l) * 64;
#pragma unroll
        for (int q8 = 0; q8 < 8; ++q8)
            *(h8*)(tgt + base + q8 * 8) = *(h8*)(Ol + row * 136 + half * 64 + q8 * 8);
    }
}

// ------------------------- M[ch] = min_l nk -------------------------------
__global__ __launch_bounds__(256) void k_minred(const float* __restrict__ nk,
                                                float* __restrict__ MG) {
    const int ch = blockIdx.x;
    const int tid = threadIdx.x;
    __shared__ float red[4];
    float v = 1e30f;
    for (int i = tid; i < 4096; i += 256) v = fminf(v, nk[(size_t)ch * 4096 + i]);
#pragma unroll
    for (int off = 32; off >= 1; off >>= 1) v = fminf(v, __shfl_down(v, off));
    if ((tid & 63) == 0) red[tid >> 6] = v;
    __syncthreads();
    if (tid == 0) MG[ch] = fminf(fminf(red[0], red[1]), fminf(red[2], red[3]));
}

// ------------------------- kvstats: St[d][f], sumk ------------------------
__global__ __launch_bounds__(256) void k_kvstats(const _Float16* __restrict__ kb,
                                                 const _Float16* __restrict__ vb,
                                                 const float* __restrict__ nkG,
                                                 const _Float16* __restrict__ atfG,
                                                 const float* __restrict__ MG,
                                                 float* __restrict__ St,
                                                 float* __restrict__ sumk) {
    __shared__ char smem[29824];
    _Float16* kl = (_Float16*)smem;              // [8 ks][32 l][8]
    _Float16* vt = kl + 2048;                    // [64 d][40]
    _Float16* pt = vt + 2560;                    // [256 f][40]
    float* nks = (float*)(pt + 10240);           // [32]

    const int tid = threadIdx.x;
    const int lane = tid & 63, w = tid >> 6;
    const int lane16 = lane & 15, lrow = lane >> 4;
    const int ch = blockIdx.x, split = blockIdx.y;
    const int h = ch & 15;
    const _Float16* atfH = atfG + (size_t)h * 16384;
    const float Mch = MG[ch];

    f32x4 Sacc[4][4];
    const f32x4 zz = {0.f, 0.f, 0.f, 0.f};
#pragma unroll
    for (int i = 0; i < 4; ++i)
#pragma unroll
        for (int j = 0; j < 4; ++j) Sacc[i][j] = zz;
    float skr[4][4] = {};

    for (int chunk = 0; chunk < 16; ++chunk) {
        const int l0 = split * 512 + chunk * 32;
        __syncthreads();
        {
            const int g = w * 64 + lane;
            GLDS16(kb + ((size_t)ch * 4096 + l0 + (g & 31)) * 64 + (g >> 5) * 8, kl + g * 8);
        }
        {
            const int l = tid >> 3, d0 = (tid & 7) * 8;
            const h8 vv = *(const h8*)(vb + ((size_t)ch * 4096 + l0 + l) * 64 + d0);
#pragma unroll
            for (int j = 0; j < 8; ++j) vt[(d0 + j) * 40 + l] = vv[j];
        }
        if (tid < 32) nks[tid] = nkG[(size_t)ch * 4096 + l0 + tid];
        __syncthreads();
        // phi^T: C[f][l] = sum_d Atf[f][d]*K[l][d]
        f32x4 p[4][2];
#pragma unroll
        for (int i = 0; i < 4; ++i) { p[i][0] = zz; p[i][1] = zz; }
#pragma unroll
        for (int ks = 0; ks < 2; ++ks) {
            const int kd = ks * 4 + lrow;
            h8 bfr[2];
#pragma unroll
            for (int nf = 0; nf < 2; ++nf)
                bfr[nf] = *(h8*)(kl + (kd * 32 + nf * 16 + lane16) * 8);
#pragma unroll
            for (int mf = 0; mf < 4; ++mf) {
                const int f = w * 64 + mf * 16 + lane16;
                const h8 a = *(const h8*)(atfH + (size_t)f * 64 + kd * 8);
#pragma unroll
                for (int nf = 0; nf < 2; ++nf)
                    p[mf][nf] = __builtin_amdgcn_mfma_f32_16x16x32_f16(a, bfr[nf], p[mf][nf], 0, 0, 0);
            }
        }
#pragma unroll
        for (int mf = 0; mf < 4; ++mf)
#pragma unroll
            for (int nf = 0; nf < 2; ++nf) {
                const int ll = nf * 16 + lane16;
                const float nv = nks[ll];
#pragma unroll
                for (int r = 0; r < 4; ++r) {
                    const float e = expf(p[mf][nf][r] - nv + Mch);
                    skr[mf][r] += e;
                    const int fr = w * 64 + mf * 16 + lrow * 4 + r;
                    pt[fr * 40 + ll] = (_Float16)e;
                }
            }
        __syncthreads();
        // St: C[d][f] = sum_l Vt[d][l]*Pt[f][l]
        h8 bfr2[4];
#pragma unroll
        for (int nf = 0; nf < 4; ++nf)
            bfr2[nf] = *(h8*)(pt + (w * 64 + nf * 16 + lane16) * 40 + lrow * 8);
#pragma unroll
        for (int mf = 0; mf < 4; ++mf) {
            const h8 a = *(h8*)(vt + (mf * 16 + lane16) * 40 + lrow * 8);
#pragma unroll
            for (int nf = 0; nf < 4; ++nf)
                Sacc[mf][nf] = __builtin_amdgcn_mfma_f32_16x16x32_f16(a, bfr2[nf], Sacc[mf][nf], 0, 0, 0);
        }
    }
#pragma unroll
    for (int mf = 0; mf < 4; ++mf)
#pragma unroll
        for (int nf = 0; nf < 4; ++nf)
#pragma unroll
            for (int r = 0; r < 4; ++r) {
                const int d = mf * 16 + lrow * 4 + r;
                const int f = w * 64 + nf * 16 + lane16;
                atomicAdd(&St[((size_t)ch * 64 + d) * 256 + f], Sacc[mf][nf][r]);
            }
#pragma unroll
    for (int mf = 0; mf < 4; ++mf) {
#pragma unroll
        for (int m = 1; m < 16; m <<= 1)
#pragma unroll
            for (int r = 0; r < 4; ++r) skr[mf][r] += __shfl_xor(skr[mf][r], m);
        if (lane16 == 0)
#pragma unroll
            for (int r = 0; r < 4; ++r)
                atomicAdd(&sumk[(size_t)ch * 256 + w * 64 + mf * 16 + lrow * 4 + r], skr[mf][r]);
    }
}

// ------------------------- St fp32 -> Stb fp16 [ch][80][256] --------------
__global__ __launch_bounds__(256) void k_cvt_st(const float* __restrict__ St,
                                                const float* __restrict__ sumk,
                                                _Float16* __restrict__ Stb) {
    const size_t n = (size_t)64 * 80 * 256;
    const size_t st = (size_t)gridDim.x * 256;
    for (size_t e = (size_t)blockIdx.x * 256 + threadIdx.x; e < n; e += st) {
        const int f = (int)(e & 255);
        const int row = (int)((e >> 8) % 80);
        const int ch = (int)(e / (80 * 256));
        float v = 0.0f;
        if (row < 64) v = St[((size_t)ch * 64 + row) * 256 + f];
        else if (row == 64) v = sumk[(size_t)ch * 256 + f];
        Stb[e] = (_Float16)(v * SIGMA);
    }
}

// ------------------------- attn: oh = numer / max(denom, T) ---------------
__global__ __launch_bounds__(256) void k_attn(const _Float16* __restrict__ qb,
                                              const float* __restrict__ nqG,
                                              const _Float16* __restrict__ atfG,
                                              const _Float16* __restrict__ Stb,
                                              const float* __restrict__ MG,
                                              _Float16* __restrict__ oh) {
    __shared__ char smem[41216];
    _Float16* pq = (_Float16*)smem;              // [32 ks][64 l][8]
    _Float16* ql = pq + 16384;                   // [8 ks][64 l][8]
    float* nqs = (float*)(ql + 4096);            // [64]
    _Float16* olds = pq;                         // overlay [64][72]

    const int tid = threadIdx.x;
    const int lane = tid & 63, w = tid >> 6;
    const int lane16 = lane & 15, lrow = lane >> 4;
    const int ch = blockIdx.x, lb = blockIdx.y;
    const int h = ch & 15, c = ch >> 4;
    const int l0 = lb * 64;
    const _Float16* atfH = atfG + (size_t)h * 16384;
    const _Float16* stbH = Stb + (size_t)ch * 20480;
    const float Mch = MG[ch];

#pragma unroll
    for (int j = 0; j < 2; ++j) {
        const int g = (w * 2 + j) * 64 + lane;
        GLDS16(qb + ((size_t)ch * 4096 + l0 + (g & 63)) * 64 + (g >> 6) * 8, ql + g * 8);
    }
    if (tid < 64) nqs[tid] = nqG[(size_t)ch * 4096 + l0 + tid];
    __syncthreads();

    const f32x4 zz = {0.f, 0.f, 0.f, 0.f};
    // phi_q: C[l][f] = sum_d Q[l][d]*Atf[f][d]; wave w owns rows w*16..+16
    {
        f32x4 p[16];
#pragma unroll
        for (int nf = 0; nf < 16; ++nf) p[nf] = zz;
#pragma unroll
        for (int ks = 0; ks < 2; ++ks) {
            const int kd = ks * 4 + lrow;
            const h8 a = *(h8*)(ql + (kd * 64 + w * 16 + lane16) * 8);
#pragma unroll
            for (int nf = 0; nf < 16; ++nf) {
                const int f = nf * 16 + lane16;
                const h8 b = *(const h8*)(atfH + (size_t)f * 64 + kd * 8);
                p[nf] = __builtin_amdgcn_mfma_f32_16x16x32_f16(a, b, p[nf], 0, 0, 0);
            }
        }
#pragma unroll
        for (int nf = 0; nf < 16; ++nf) {
            const int f = nf * 16 + lane16;
#pragma unroll
            for (int r = 0; r < 4; ++r) {
                const float e = expf(p[nf][r]);   // no norm subtract (folded into T)
                const int l = w * 16 + lrow * 4 + r;
                pq[((f >> 3) * 64 + l) * 8 + (f & 7)] = (_Float16)e;
            }
        }
    }
    __syncthreads();
    // numer/denom: C[l][dd<80] = sum_f Pq[l][f]*Stb[dd][f]
    f32x4 nacc[5];
#pragma unroll
    for (int nf = 0; nf < 5; ++nf) nacc[nf] = zz;
#pragma unroll
    for (int ks = 0; ks < 8; ++ks) {
        const int kd = ks * 4 + lrow;
        const h8 a = *(h8*)(pq + (kd * 64 + w * 16 + lane16) * 8);
#pragma unroll
        for (int nf = 0; nf < 5; ++nf) {
            const int dd = nf * 16 + lane16;
            const h8 b = *(const h8*)(stbH + (size_t)dd * 256 + kd * 8);
            nacc[nf] = __builtin_amdgcn_mfma_f32_16x16x32_f16(a, b, nacc[nf], 0, 0, 0);
        }
    }
    __syncthreads();
    {
#pragma unroll
        for (int r = 0; r < 4; ++r) {
            const float dn = __shfl(nacc[4][r], (lane & 48));  // dd==64 col
            const int row = w * 16 + lrow * 4 + r;
            const float t = expf(nqs[row] + Mch - TCONST);
            const float rden = 1.0f / fmaxf(dn, t);
#pragma unroll
            for (int nf = 0; nf < 4; ++nf)
                olds[row * 72 + nf * 16 + lane16] = (_Float16)(nacc[nf][r] * rden);
        }
    }
    __syncthreads();
    {
        const int row = tid >> 2, d0 = (tid & 3) * 16;
        const size_t base = ((size_t)c * 4096 + l0 + row) * 1024 + h * 64 + d0;
        *(h8*)(oh + base) = *(h8*)(olds + row * 72 + d0);
        *(h8*)(oh + base + 8) = *(h8*)(olds + row * 72 + d0 + 8);
    }
}

// ------------------------- out = oh @ wob^T (fp16 MFMA, 2-phase dbuf) -----
__global__ __launch_bounds__(256) void k_outgemm(const _Float16* __restrict__ OH,
                                                 const _Float16* __restrict__ WOB,
                                                 float* __restrict__ OUT) {
    __shared__ char smem[65536];

    const int tid = threadIdx.x;
    const int lane = tid & 63, w = tid >> 6;
    const int lane16 = lane & 15, lrow = lane >> 4;
    const int wm = w >> 1, wn = w & 1;

    const int per = gridDim.x >> 3;
    const int sw = ((int)blockIdx.x & 7) * per + ((int)blockIdx.x >> 3);
    const int bn = sw & 7, bm = sw >> 3;        // nbn = 8
    const int m0 = bm * 128, n0 = bn * 128;

    f32x4 acc[4][4];
    const f32x4 zz = {0.f, 0.f, 0.f, 0.f};
#pragma unroll
    for (int i = 0; i < 4; ++i)
#pragma unroll
        for (int j = 0; j < 4; ++j) acc[i][j] = zz;

    {
        _Float16* Ad = (_Float16*)smem;
        _Float16* Bd = (_Float16*)smem + 16384;
#pragma unroll
        for (int s = 0; s < 4; ++s) {
            const int g = s * 256 + tid;
            const int row = g & 127, ks = g >> 7;
            GLDS16(OH + (size_t)(m0 + row) * 1024 + ks * 8, Ad + g * 8);
            GLDS16(WOB + (size_t)(n0 + row) * 1024 + ks * 8, Bd + g * 8);
        }
    }
    __syncthreads();

    int cur = 0;
    for (int it = 0; it < 16; ++it) {
        if (it < 15) {
            const int kt = (it + 1) * 64;
            _Float16* Ad = (_Float16*)smem + (cur ^ 1) * 8192;
            _Float16* Bd = (_Float16*)smem + 16384 + (cur ^ 1) * 8192;
#pragma unroll
            for (int s = 0; s < 4; ++s) {
                const int g = s * 256 + tid;
                const int row = g & 127, ks = g >> 7;
                GLDS16(OH + (size_t)(m0 + row) * 1024 + kt + ks * 8, Ad + g * 8);
                GLDS16(WOB + (size_t)(n0 + row) * 1024 + kt + ks * 8, Bd + g * 8);
            }
        }
        const _Float16* Ah = (_Float16*)smem + cur * 8192;
        const _Float16* Bh = (_Float16*)smem + 16384 + cur * 8192;
#pragma unroll
        for (int s = 0; s < 2; ++s) {
            const int kd = s * 4 + lrow;
            h8 af[4], bf[4];
#pragma unroll
            for (int i = 0; i < 4; ++i)
                af[i] = *(const h8*)(Ah + (kd * 128 + wm * 64 + i * 16 + lane16) * 8);
#pragma unroll
            for (int j = 0; j < 4; ++j)
                bf[j] = *(const h8*)(Bh + (kd * 128 + wn * 64 + j * 16 + lane16) * 8);
#pragma unroll
            for (int i = 0; i < 4; ++i)
#pragma unroll
                for (int j = 0; j < 4; ++j)
                    acc[i][j] = __builtin_amdgcn_mfma_f32_16x16x32_f16(af[i], bf[j], acc[i][j], 0, 0, 0);
        }
        __syncthreads();
        cur ^= 1;
    }
#pragma unroll
    for (int i = 0; i < 4; ++i)
#pragma unroll
        for (int j = 0; j < 4; ++j)
#pragma unroll
            for (int r = 0; r < 4; ++r) {
                const int gm = m0 + wm * 64 + i * 16 + lrow * 4 + r;
                const int gn = n0 + wn * 64 + j * 16 + lane16;
                OUT[(size_t)gm * 1024 + gn] = acc[i][j][r];
            }
}

// ------------------------- launcher ----------------------------------------
extern "C" void kernel_launch(void* const* d_in, const int* in_sizes, int n_in,
                              void* d_out, int out_size, void* d_ws, size_t ws_size,
                              hipStream_t stream) {
    const float* x      = (const float*)d_in[0];
    const float* w_qkv  = (const float*)d_in[1];
    const float* w_out  = (const float*)d_in[2];
    const float* signs  = (const float*)d_in[3];
    const float* scales = (const float*)d_in[4];
    float* out = (float*)d_out;

    _Float16* hs = (_Float16*)d_ws;
    _Float16* xh  = hs;                       // 16,777,216
    _Float16* wh  = xh + 16777216;            // 3,145,728
    _Float16* wob = wh + 3145728;             // 1,048,576
    _Float16* kb  = wob + 1048576;            // 16,777,216  (qb overlays)
    _Float16* vb  = kb + 16777216;            // 16,777,216  (oh overlays)
    _Float16* atf = vb + 16777216;            // 262,144
    _Float16* stb = atf + 262144;             // 1,310,720
    float* St   = (float*)(stb + 1310720);    // 1,048,576
    float* sumk = St + 1048576;               // 16,384
    float* nq   = sumk + 16384;               // 262,144
    float* nk   = nq + 262144;                // 262,144
    float* MG   = nk + 262144;                // 64
    _Float16* qb = kb;                        // overlay (kb dead after kvstats)
    _Float16* oh = vb;                        // overlay (vb dead after kvstats)

    k_cvt_xw<<<dim3(1024), dim3(256), 0, stream>>>(x, w_qkv, w_out, xh, wh, wob);
    k_build_atf<<<dim3(64), dim3(64), 0, stream>>>(signs, scales, atf);
    k_zero<<<dim3(1024), dim3(256), 0, stream>>>(St, (size_t)1048576 + 16384);
    // pass 1: K,V (cols 1024..3071): nwg = 16*128 = 2048 (1D, swizzled)
    k_qkv_f16<<<dim3(2048), dim3(256), 0, stream>>>(xh, wh, qb, kb, vb, nq, nk, 1024, 16);
    k_minred<<<dim3(64), dim3(256), 0, stream>>>(nk, MG);
    k_kvstats<<<dim3(64, 8), dim3(256), 0, stream>>>(kb, vb, nk, atf, MG, St, sumk);
    k_cvt_st<<<dim3(1280), dim3(256), 0, stream>>>(St, sumk, stb);
    // pass 2: Q (cols 0..1023): nwg = 8*128 = 1024 (1D, swizzled)
    k_qkv_f16<<<dim3(1024), dim3(256), 0, stream>>>(xh, wh, qb, kb, vb, nq, nk, 0, 8);
    k_attn<<<dim3(64, 64), dim3(256), 0, stream>>>(qb, nq, atf, stb, MG, oh);
    k_outgemm<<<dim3(1024), dim3(256), 0, stream>>>(oh, wob, out);
}

// Round 8
// 661.365 us; speedup vs baseline: 3.8795x; 1.0725x over previous
//
#include <hip/hip_runtime.h>
#include <math.h>

// ---------------------------------------------------------------------------
// FastAttention — fp16 MFMA pipeline, R8: 6 kernels (was 10).
//  k_pre     : cvt x/w_qkv/w_out -> fp16, zero St/sumk, build Atf  (merged)
//  k_qkv_f16 : pass1 K,V GEMM + fast-RoPE + norms (Cody-Waite + v_sin/v_cos)
//  k_kvstats : local min(nk)->MG, chunk-prefetch (T14), St/sumk atomics
//  k_mid     : [qkv pass2 Q] ∥ [cvt_st]  (independent; merged launch)
//  k_attn    : qphi MFMA; numer/denom; LDS=40960 (4 blocks/CU), norms in regs
//  k_outgemm : out = oh @ wob^T
// Scaling algebra unchanged from R6/R7 (threshold folded: exact vs reference).
// ---------------------------------------------------------------------------

#define LOG2_10000 13.287712379549449f
#define TCONST 15.201805f   // -ln(1e-6 * 256 * 2^-10)
#define SIGMA 0.0009765625f // 2^-10
#define INV2PI 0.15915494309189535f
#define INV2PI_ERR 6.4206383e-9f

typedef __attribute__((ext_vector_type(8))) _Float16 h8;
typedef __attribute__((ext_vector_type(4))) _Float16 h4;
typedef __attribute__((ext_vector_type(4))) float f32x4;

#define GLDS16(gptr, lptr) __builtin_amdgcn_global_load_lds( \
    (const __attribute__((address_space(1))) void*)(gptr),   \
    (__attribute__((address_space(3))) void*)(lptr), 16, 0, 0)

// fast sin/cos of ang radians via revolutions + Cody-Waite reduction
static __device__ __forceinline__ void fast_sincos(float ang, float* sn, float* cs) {
    const float t = ang * INV2PI;
    const float k = floorf(t);
    float r = fmaf(ang, INV2PI, -k);        // single rounding, |r| ~ [0,1)
    r = fmaf(ang, INV2PI_ERR, r);           // correct fl(1/2pi) error
    *sn = __builtin_amdgcn_sinf(r);         // sin(2*pi*r)
    *cs = __builtin_amdgcn_cosf(r);
}

// ------------------------- k_pre: cvt + zero + build_atf -------------------
__global__ __launch_bounds__(256) void k_pre(const float* __restrict__ x,
                                             const float* __restrict__ wqkv,
                                             const float* __restrict__ wout,
                                             _Float16* __restrict__ xh,
                                             _Float16* __restrict__ wh,
                                             _Float16* __restrict__ wob,
                                             float* __restrict__ zbase,
                                             const float* __restrict__ signs,
                                             const float* __restrict__ scales,
                                             _Float16* __restrict__ atfG) {
    const int bid = blockIdx.x;
    const int tid = threadIdx.x;
    if (bid < 2048) {
        const size_t st = (size_t)2048 * 256;
        const size_t nx = (size_t)16384 * 1024 / 4;
        for (size_t i = (size_t)bid * 256 + tid; i < nx; i += st) {
            float4 v = ((const float4*)x)[i];
            h4 o = {(_Float16)v.x, (_Float16)v.y, (_Float16)v.z, (_Float16)v.w};
            ((h4*)xh)[i] = o;
        }
        const size_t nw = (size_t)3072 * 1024 / 4;
        for (size_t i = (size_t)bid * 256 + tid; i < nw; i += st) {
            float4 v = ((const float4*)wqkv)[i];
            h4 o = {(_Float16)v.x, (_Float16)v.y, (_Float16)v.z, (_Float16)v.w};
            ((h4*)wh)[i] = o;
        }
        const size_t no = (size_t)1024 * 1024 / 4;
        for (size_t i = (size_t)bid * 256 + tid; i < no; i += st) {
            float4 v = ((const float4*)wout)[i];
            h4 o = {(_Float16)v.x, (_Float16)v.y, (_Float16)v.z, (_Float16)v.w};
            ((h4*)wob)[i] = o;
        }
        const size_t nz = (size_t)1048576 + 16384;   // St + sumk
        for (size_t i = (size_t)bid * 256 + tid; i < nz; i += st) zbase[i] = 0.0f;
    } else if (tid < 64) {
        const int b = bid - 2048;          // h*4 + r
        const int hh = b >> 2, r = b & 3;
        const int j = tid;
        const float* s1 = signs + ((size_t)(hh * 4 + r) * 3 + 0) * 64;
        const float* s2 = s1 + 64;
        const float* s3 = s1 + 128;
        const float* sc = scales + (size_t)(hh * 4 + r) * 64;
        float v[64];
        const float s1j = s1[j];
#pragma unroll
        for (int p = 0; p < 64; ++p) v[p] = (p == j) ? s1j : 0.0f;
#pragma unroll
        for (int st2 = 1; st2 < 64; st2 <<= 1)
#pragma unroll
            for (int p = 0; p < 64; ++p)
                if (!(p & st2)) { float a = v[p], bq = v[p | st2]; v[p] = a + bq; v[p | st2] = a - bq; }
#pragma unroll
        for (int p = 0; p < 64; ++p) v[p] *= s2[p];
#pragma unroll
        for (int st2 = 1; st2 < 64; st2 <<= 1)
#pragma unroll
            for (int p = 0; p < 64; ++p)
                if (!(p & st2)) { float a = v[p], bq = v[p | st2]; v[p] = a + bq; v[p | st2] = a - bq; }
#pragma unroll
        for (int p = 0; p < 64; ++p) v[p] *= s3[p];
#pragma unroll
        for (int st2 = 1; st2 < 64; st2 <<= 1)
#pragma unroll
            for (int p = 0; p < 64; ++p)
                if (!(p & st2)) { float a = v[p], bq = v[p | st2]; v[p] = a + bq; v[p | st2] = a - bq; }
#pragma unroll
        for (int p = 0; p < 64; ++p)
            atfG[((size_t)hh * 256 + r * 64 + p) * 64 + j] = (_Float16)(v[p] * sc[p] * (1.0f / 4096.0f));
    }
}

// ------------------------- qkv GEMM body (shared by pass1/pass2) ----------
static __device__ __forceinline__ void qkv_body(char* smem,
                                                const _Float16* __restrict__ xh,
                                                const _Float16* __restrict__ wh,
                                                _Float16* __restrict__ qb,
                                                _Float16* __restrict__ kb,
                                                _Float16* __restrict__ vb,
                                                float* __restrict__ nq,
                                                float* __restrict__ nk,
                                                int swid, int n_base, int nbn, int nwg) {
    _Float16* Ol = (_Float16*)smem;          // epilogue overlay [128][136]
    const int tid = threadIdx.x;
    const int lane = tid & 63, w = tid >> 6;
    const int lane16 = lane & 15, lrow = lane >> 4;
    const int wm = w >> 1, wn = w & 1;

    const int per = nwg >> 3;
    const int sw = (swid & 7) * per + (swid >> 3);
    const int bn = sw % nbn, bm = sw / nbn;
    const int m0 = bm * 128, n0 = n_base + bn * 128;

    f32x4 acc[4][4];
    const f32x4 zz = {0.f, 0.f, 0.f, 0.f};
#pragma unroll
    for (int i = 0; i < 4; ++i)
#pragma unroll
        for (int j = 0; j < 4; ++j) acc[i][j] = zz;

    // prologue: stage tile 0 into buf 0
    {
        _Float16* Ad = (_Float16*)smem;
        _Float16* Bd = (_Float16*)smem + 16384;
#pragma unroll
        for (int s = 0; s < 4; ++s) {
            const int g = s * 256 + tid;
            const int row = g & 127, ks = g >> 7;
            GLDS16(xh + (size_t)(m0 + row) * 1024 + ks * 8, Ad + g * 8);
            GLDS16(wh + (size_t)(n0 + row) * 1024 + ks * 8, Bd + g * 8);
        }
    }
    __syncthreads();

    int cur = 0;
    for (int it = 0; it < 16; ++it) {
        if (it < 15) {
            const int kt = (it + 1) * 64;
            _Float16* Ad = (_Float16*)smem + (cur ^ 1) * 8192;
            _Float16* Bd = (_Float16*)smem + 16384 + (cur ^ 1) * 8192;
#pragma unroll
            for (int s = 0; s < 4; ++s) {
                const int g = s * 256 + tid;
                const int row = g & 127, ks = g >> 7;
                GLDS16(xh + (size_t)(m0 + row) * 1024 + kt + ks * 8, Ad + g * 8);
                GLDS16(wh + (size_t)(n0 + row) * 1024 + kt + ks * 8, Bd + g * 8);
            }
        }
        const _Float16* Ah = (_Float16*)smem + cur * 8192;
        const _Float16* Bh = (_Float16*)smem + 16384 + cur * 8192;
#pragma unroll
        for (int s = 0; s < 2; ++s) {
            const int kd = s * 4 + lrow;
            h8 af[4], bf[4];
#pragma unroll
            for (int i = 0; i < 4; ++i)
                af[i] = *(const h8*)(Ah + (kd * 128 + wm * 64 + i * 16 + lane16) * 8);
#pragma unroll
            for (int j = 0; j < 4; ++j)
                bf[j] = *(const h8*)(Bh + (kd * 128 + wn * 64 + j * 16 + lane16) * 8);
#pragma unroll
            for (int i = 0; i < 4; ++i)
#pragma unroll
                for (int j = 0; j < 4; ++j)
                    acc[i][j] = __builtin_amdgcn_mfma_f32_16x16x32_f16(af[i], bf[j], acc[i][j], 0, 0, 0);
        }
        __syncthreads();
        cur ^= 1;
    }

    // epilogue: fast RoPE -> round fp16 -> norms (from rounded) -> store
    const int sec = n0 >> 10;  // 0=q 1=k 2=v (block-uniform)
    float freqj[4];
#pragma unroll
    for (int j = 0; j < 4; ++j) {
        const int colw = wn * 64 + j * 16 + lane16;
        freqj[j] = exp2f(-(float)((colw & 63) & ~1) * (LOG2_10000 / 64.0f));
    }

#pragma unroll
    for (int i = 0; i < 4; ++i) {
        float nsum[4] = {0.f, 0.f, 0.f, 0.f};
#pragma unroll
        for (int j = 0; j < 4; ++j) {
            const int colw = wn * 64 + j * 16 + lane16;
#pragma unroll
            for (int r = 0; r < 4; ++r) {
                float v = acc[i][j][r];
                const float partner = __shfl_xor(v, 1);
                const int gm = m0 + wm * 64 + i * 16 + lrow * 4 + r;
                const int l = gm & 4095;
                if (sec < 2 && l > 0) {
                    float sn, cs;
                    fast_sincos((float)(l - 1) * freqj[j], &sn, &cs);
                    v = v * cs + sn * ((lane & 1) ? partner : -partner);
                }
                const _Float16 hv = (_Float16)v;
                if (sec < 2) {
                    const float vr = (float)hv;
                    nsum[r] += vr * vr;
                }
                Ol[(wm * 64 + i * 16 + lrow * 4 + r) * 136 + colw] = hv;
            }
        }
        if (sec < 2) {
#pragma unroll
            for (int m = 1; m < 16; m <<= 1)
#pragma unroll
                for (int r = 0; r < 4; ++r) nsum[r] += __shfl_xor(nsum[r], m);
            if (lane16 == 0) {
                float* ntgt = (sec == 0) ? nq : nk;
                const int hh = ((unsigned)(n0 + wn * 64) >> 6) & 15;
#pragma unroll
                for (int r = 0; r < 4; ++r) {
                    const int gm = m0 + wm * 64 + i * 16 + lrow * 4 + r;
                    const int c = gm >> 12, l = gm & 4095;
                    ntgt[((size_t)(c * 16 + hh)) * 4096 + l] = 0.5f * nsum[r];
                }
            }
        }
    }
    __syncthreads();
    // coalesced copy-out: wave stores 1KB contiguous per iteration
    {
        _Float16* tgt = (sec == 0) ? qb : (sec == 1) ? kb : vb;
#pragma unroll
        for (int t2 = 0; t2 < 8; ++t2) {
            const int g = t2 * 256 + tid;
            const int half = g >> 10, r = (g >> 3) & 127, d8 = g & 7;
            const int gm = m0 + r;
            const int c = gm >> 12, l = gm & 4095;
            const int hh = ((unsigned)(n0 + half * 64) >> 6) & 15;
            const size_t base = ((size_t)(c * 16 + hh) * 4096 + l) * 64 + d8 * 8;
            *(h8*)(tgt + base) = *(h8*)(Ol + r * 136 + half * 64 + d8 * 8);
        }
    }
}

__global__ __launch_bounds__(256) void k_qkv_f16(const _Float16* __restrict__ xh,
                                                 const _Float16* __restrict__ wh,
                                                 _Float16* __restrict__ qb,
                                                 _Float16* __restrict__ kb,
                                                 _Float16* __restrict__ vb,
                                                 float* __restrict__ nq,
                                                 float* __restrict__ nk,
                                                 int n_base, int nbn, int nwg) {
    __shared__ char smem[65536];
    qkv_body(smem, xh, wh, qb, kb, vb, nq, nk, (int)blockIdx.x, n_base, nbn, nwg);
}

// ------------------------- kvstats: local-min + prefetch ------------------
__global__ __launch_bounds__(256) void k_kvstats(const _Float16* __restrict__ kb,
                                                 const _Float16* __restrict__ vb,
                                                 const float* __restrict__ nkG,
                                                 const _Float16* __restrict__ atfG,
                                                 float* __restrict__ MG,
                                                 float* __restrict__ St,
                                                 float* __restrict__ sumk) {
    __shared__ char smem[38944];
    _Float16* kl0 = (_Float16*)smem;             // 2 x [8 ks][32 l][8] = 2x4096B
    _Float16* kl1 = kl0 + 2048;
    _Float16* vt0 = kl1 + 2048;                  // 2 x [64 d][40] = 2x5120B
    _Float16* vt1 = vt0 + 2560;
    _Float16* pt  = vt1 + 2560;                  // [256 f][40] = 20480B
    float* red = (float*)(pt + 10240);           // [4]

    const int tid = threadIdx.x;
    const int lane = tid & 63, w = tid >> 6;
    const int lane16 = lane & 15, lrow = lane >> 4;
    const int ch = blockIdx.x, split = blockIdx.y;
    const int h = ch & 15;
    const _Float16* atfH = atfG + (size_t)h * 16384;
    const int lv = tid >> 3, d0v = (tid & 7) * 8;

    // local min over full nk[ch] (order-independent -> identical across blocks)
    float mv = 1e30f;
    for (int i = tid; i < 4096; i += 256) mv = fminf(mv, nkG[(size_t)ch * 4096 + i]);
#pragma unroll
    for (int off = 32; off >= 1; off >>= 1) mv = fminf(mv, __shfl_xor(mv, off));
    if (lane == 0) red[w] = mv;
    __syncthreads();
    const float Mch = fminf(fminf(red[0], red[1]), fminf(red[2], red[3]));
    if (tid == 0) MG[ch] = Mch;   // benign duplicate identical writes

    f32x4 Sacc[4][4];
    const f32x4 zz = {0.f, 0.f, 0.f, 0.f};
#pragma unroll
    for (int i = 0; i < 4; ++i)
#pragma unroll
        for (int j = 0; j < 4; ++j) Sacc[i][j] = zz;
    float skr[4][4] = {};

    // prologue: stage chunk 0
    {
        const int g = w * 64 + lane;
        GLDS16(kb + ((size_t)ch * 4096 + split * 512 + (g & 31)) * 64 + (g >> 5) * 8, kl0 + g * 8);
    }
    h8 vreg = *(const h8*)(vb + ((size_t)ch * 4096 + split * 512 + lv) * 64 + d0v);
    __syncthreads();
#pragma unroll
    for (int j = 0; j < 8; ++j) vt0[(d0v + j) * 40 + lv] = vreg[j];

    for (int chunk = 0; chunk < 16; ++chunk) {
        const int cur = chunk & 1;
        const int l0 = split * 512 + chunk * 32;
        _Float16* klc = cur ? kl1 : kl0;
        _Float16* kln = cur ? kl0 : kl1;
        _Float16* vtc = cur ? vt1 : vt0;
        _Float16* vtn = cur ? vt0 : vt1;
        if (chunk < 15) {
            const int l0n = l0 + 32;
            const int g = w * 64 + lane;
            GLDS16(kb + ((size_t)ch * 4096 + l0n + (g & 31)) * 64 + (g >> 5) * 8, kln + g * 8);
            vreg = *(const h8*)(vb + ((size_t)ch * 4096 + l0n + lv) * 64 + d0v);
        }
        const float nv0 = nkG[(size_t)ch * 4096 + l0 + lane16];
        const float nv1 = nkG[(size_t)ch * 4096 + l0 + 16 + lane16];
        // phase A: phi^T MFMA on klc
        f32x4 p[4][2];
#pragma unroll
        for (int i = 0; i < 4; ++i) { p[i][0] = zz; p[i][1] = zz; }
#pragma unroll
        for (int ks = 0; ks < 2; ++ks) {
            const int kd = ks * 4 + lrow;
            h8 bfr[2];
#pragma unroll
            for (int nf = 0; nf < 2; ++nf)
                bfr[nf] = *(h8*)(klc + (kd * 32 + nf * 16 + lane16) * 8);
#pragma unroll
            for (int mf = 0; mf < 4; ++mf) {
                const int f = w * 64 + mf * 16 + lane16;
                const h8 a = *(const h8*)(atfH + (size_t)f * 64 + kd * 8);
#pragma unroll
                for (int nf = 0; nf < 2; ++nf)
                    p[mf][nf] = __builtin_amdgcn_mfma_f32_16x16x32_f16(a, bfr[nf], p[mf][nf], 0, 0, 0);
            }
        }
#pragma unroll
        for (int mf = 0; mf < 4; ++mf)
#pragma unroll
            for (int nf = 0; nf < 2; ++nf) {
                const int ll = nf * 16 + lane16;
                const float nvv = nf ? nv1 : nv0;
#pragma unroll
                for (int r = 0; r < 4; ++r) {
                    const float e = expf(p[mf][nf][r] - nvv + Mch);
                    skr[mf][r] += e;
                    const int fr = w * 64 + mf * 16 + lrow * 4 + r;
                    pt[fr * 40 + ll] = (_Float16)e;
                }
            }
        __syncthreads();   // pt visible; kln landed; vtc visible
        // phase B: Sacc += Vt^T Pt
        h8 bfr2[4];
#pragma unroll
        for (int nf = 0; nf < 4; ++nf)
            bfr2[nf] = *(h8*)(pt + (w * 64 + nf * 16 + lane16) * 40 + lrow * 8);
#pragma unroll
        for (int mf = 0; mf < 4; ++mf) {
            const h8 a = *(h8*)(vtc + (mf * 16 + lane16) * 40 + lrow * 8);
#pragma unroll
            for (int nf = 0; nf < 4; ++nf)
                Sacc[mf][nf] = __builtin_amdgcn_mfma_f32_16x16x32_f16(a, bfr2[nf], Sacc[mf][nf], 0, 0, 0);
        }
        if (chunk < 15) {
#pragma unroll
            for (int j = 0; j < 8; ++j) vtn[(d0v + j) * 40 + lv] = vreg[j];
        }
        __syncthreads();   // protect pt overwrite + vtn visibility
    }
#pragma unroll
    for (int mf = 0; mf < 4; ++mf)
#pragma unroll
        for (int nf = 0; nf < 4; ++nf)
#pragma unroll
            for (int r = 0; r < 4; ++r) {
                const int d = mf * 16 + lrow * 4 + r;
                const int f = w * 64 + nf * 16 + lane16;
                atomicAdd(&St[((size_t)ch * 64 + d) * 256 + f], Sacc[mf][nf][r]);
            }
#pragma unroll
    for (int mf = 0; mf < 4; ++mf) {
#pragma unroll
        for (int m = 1; m < 16; m <<= 1)
#pragma unroll
            for (int r = 0; r < 4; ++r) skr[mf][r] += __shfl_xor(skr[mf][r], m);
        if (lane16 == 0)
#pragma unroll
            for (int r = 0; r < 4; ++r)
                atomicAdd(&sumk[(size_t)ch * 256 + w * 64 + mf * 16 + lrow * 4 + r], skr[mf][r]);
    }
}

// ------------------------- k_mid: qkv pass2 || cvt_st ---------------------
__global__ __launch_bounds__(256) void k_mid(const _Float16* __restrict__ xh,
                                             const _Float16* __restrict__ wh,
                                             _Float16* __restrict__ qb,
                                             _Float16* __restrict__ kb,
                                             _Float16* __restrict__ vb,
                                             float* __restrict__ nq,
                                             float* __restrict__ nk,
                                             const float* __restrict__ St,
                                             const float* __restrict__ sumk,
                                             _Float16* __restrict__ Stb) {
    __shared__ char smem[65536];
    const int bid = blockIdx.x;
    if (bid < 1024) {
        qkv_body(smem, xh, wh, qb, kb, vb, nq, nk, bid, 0, 8, 1024);
    } else {
        const size_t n = (size_t)64 * 80 * 256;
        const size_t st = (size_t)256 * 256;
        for (size_t e = (size_t)(bid - 1024) * 256 + threadIdx.x; e < n; e += st) {
            const int f = (int)(e & 255);
            const int row = (int)((e >> 8) % 80);
            const int ch = (int)(e / (80 * 256));
            float v = 0.0f;
            if (row < 64) v = St[((size_t)ch * 64 + row) * 256 + f];
            else if (row == 64) v = sumk[(size_t)ch * 256 + f];
            Stb[e] = (_Float16)(v * SIGMA);
        }
    }
}

// ------------------------- attn -------------------------------------------
__global__ __launch_bounds__(256) void k_attn(const _Float16* __restrict__ qb,
                                              const float* __restrict__ nqG,
                                              const _Float16* __restrict__ atfG,
                                              const _Float16* __restrict__ Stb,
                                              const float* __restrict__ MG,
                                              _Float16* __restrict__ oh) {
    __shared__ char smem[40960];
    _Float16* pq = (_Float16*)smem;              // [32 ks][64 l][8] = 32768B
    _Float16* ql = pq + 16384;                   // [8 ks][64 l][8] = 8192B
    _Float16* olds = pq;                         // overlay [64][72]

    const int tid = threadIdx.x;
    const int lane = tid & 63, w = tid >> 6;
    const int lane16 = lane & 15, lrow = lane >> 4;
    const int ch = blockIdx.x, lb = blockIdx.y;
    const int h = ch & 15, c = ch >> 4;
    const int l0 = lb * 64;
    const _Float16* atfH = atfG + (size_t)h * 16384;
    const _Float16* stbH = Stb + (size_t)ch * 20480;
    const float Mch = MG[ch];

#pragma unroll
    for (int j = 0; j < 2; ++j) {
        const int g = (w * 2 + j) * 64 + lane;
        GLDS16(qb + ((size_t)ch * 4096 + l0 + (g & 63)) * 64 + (g >> 6) * 8, ql + g * 8);
    }
    float nv[4];
#pragma unroll
    for (int r = 0; r < 4; ++r)
        nv[r] = nqG[(size_t)ch * 4096 + l0 + w * 16 + lrow * 4 + r];
    __syncthreads();

    const f32x4 zz = {0.f, 0.f, 0.f, 0.f};
    // phi_q: C[l][f]; wave w owns rows w*16..+16
    {
        f32x4 p[16];
#pragma unroll
        for (int nf = 0; nf < 16; ++nf) p[nf] = zz;
#pragma unroll
        for (int ks = 0; ks < 2; ++ks) {
            const int kd = ks * 4 + lrow;
            const h8 a = *(h8*)(ql + (kd * 64 + w * 16 + lane16) * 8);
#pragma unroll
            for (int nf = 0; nf < 16; ++nf) {
                const int f = nf * 16 + lane16;
                const h8 b = *(const h8*)(atfH + (size_t)f * 64 + kd * 8);
                p[nf] = __builtin_amdgcn_mfma_f32_16x16x32_f16(a, b, p[nf], 0, 0, 0);
            }
        }
#pragma unroll
        for (int nf = 0; nf < 16; ++nf) {
            const int f = nf * 16 + lane16;
#pragma unroll
            for (int r = 0; r < 4; ++r) {
                const float e = expf(p[nf][r]);   // norm folded into clamp T
                const int l = w * 16 + lrow * 4 + r;
                pq[((f >> 3) * 64 + l) * 8 + (f & 7)] = (_Float16)e;
            }
        }
    }
    __syncthreads();
    // numer/denom
    f32x4 nacc[5];
#pragma unroll
    for (int nf = 0; nf < 5; ++nf) nacc[nf] = zz;
#pragma unroll
    for (int ks = 0; ks < 8; ++ks) {
        const int kd = ks * 4 + lrow;
        const h8 a = *(h8*)(pq + (kd * 64 + w * 16 + lane16) * 8);
#pragma unroll
        for (int nf = 0; nf < 5; ++nf) {
            const int dd = nf * 16 + lane16;
            const h8 b = *(const h8*)(stbH + (size_t)dd * 256 + kd * 8);
            nacc[nf] = __builtin_amdgcn_mfma_f32_16x16x32_f16(a, b, nacc[nf], 0, 0, 0);
        }
    }
    __syncthreads();
    {
#pragma unroll
        for (int r = 0; r < 4; ++r) {
            const float dn = __shfl(nacc[4][r], (lane & 48));  // dd==64 col
            const int row = w * 16 + lrow * 4 + r;
            const float t = expf(nv[r] + Mch - TCONST);
            const float rden = 1.0f / fmaxf(dn, t);
#pragma unroll
            for (int nf = 0; nf < 4; ++nf)
                olds[row * 72 + nf * 16 + lane16] = (_Float16)(nacc[nf][r] * rden);
        }
    }
    __syncthreads();
    {
        const int row = tid >> 2, d0 = (tid & 3) * 16;
        const size_t base = ((size_t)c * 4096 + l0 + row) * 1024 + h * 64 + d0;
        *(h8*)(oh + base) = *(h8*)(olds + row * 72 + d0);
        *(h8*)(oh + base + 8) = *(h8*)(olds + row * 72 + d0 + 8);
    }
}

// ------------------------- outgemm ----------------------------------------
__global__ __launch_bounds__(256) void k_outgemm(const _Float16* __restrict__ OH,
                                                 const _Float16* __restrict__ WOB,
                                                 float* __restrict__ OUT) {
    __shared__ char smem[65536];
    const int tid = threadIdx.x;
    const int lane = tid & 63, w = tid >> 6;
    const int lane16 = lane & 15, lrow = lane >> 4;
    const int wm = w >> 1, wn = w & 1;

    const int per = gridDim.x >> 3;
    const int sw = ((int)blockIdx.x & 7) * per + ((int)blockIdx.x >> 3);
    const int bn = sw & 7, bm = sw >> 3;
    const int m0 = bm * 128, n0 = bn * 128;

    f32x4 acc[4][4];
    const f32x4 zz = {0.f, 0.f, 0.f, 0.f};
#pragma unroll
    for (int i = 0; i < 4; ++i)
#pragma unroll
        for (int j = 0; j < 4; ++j) acc[i][j] = zz;

    {
        _Float16* Ad = (_Float16*)smem;
        _Float16* Bd = (_Float16*)smem + 16384;
#pragma unroll
        for (int s = 0; s < 4; ++s) {
            const int g = s * 256 + tid;
            const int row = g & 127, ks = g >> 7;
            GLDS16(OH + (size_t)(m0 + row) * 1024 + ks * 8, Ad + g * 8);
            GLDS16(WOB + (size_t)(n0 + row) * 1024 + ks * 8, Bd + g * 8);
        }
    }
    __syncthreads();

    int cur = 0;
    for (int it = 0; it < 16; ++it) {
        if (it < 15) {
            const int kt = (it + 1) * 64;
            _Float16* Ad = (_Float16*)smem + (cur ^ 1) * 8192;
            _Float16* Bd = (_Float16*)smem + 16384 + (cur ^ 1) * 8192;
#pragma unroll
            for (int s = 0; s < 4; ++s) {
                const int g = s * 256 + tid;
                const int row = g & 127, ks = g >> 7;
                GLDS16(OH + (size_t)(m0 + row) * 1024 + kt + ks * 8, Ad + g * 8);
                GLDS16(WOB + (size_t)(n0 + row) * 1024 + kt + ks * 8, Bd + g * 8);
            }
        }
        const _Float16* Ah = (_Float16*)smem + cur * 8192;
        const _Float16* Bh = (_Float16*)smem + 16384 + cur * 8192;
#pragma unroll
        for (int s = 0; s < 2; ++s) {
            const int kd = s * 4 + lrow;
            h8 af[4], bf[4];
#pragma unroll
            for (int i = 0; i < 4; ++i)
                af[i] = *(const h8*)(Ah + (kd * 128 + wm * 64 + i * 16 + lane16) * 8);
#pragma unroll
            for (int j = 0; j < 4; ++j)
                bf[j] = *(const h8*)(Bh + (kd * 128 + wn * 64 + j * 16 + lane16) * 8);
#pragma unroll
            for (int i = 0; i < 4; ++i)
#pragma unroll
                for (int j = 0; j < 4; ++j)
                    acc[i][j] = __builtin_amdgcn_mfma_f32_16x16x32_f16(af[i], bf[j], acc[i][j], 0, 0, 0);
        }
        __syncthreads();
        cur ^= 1;
    }
#pragma unroll
    for (int i = 0; i < 4; ++i)
#pragma unroll
        for (int j = 0; j < 4; ++j)
#pragma unroll
            for (int r = 0; r < 4; ++r) {
                const int gm = m0 + wm * 64 + i * 16 + lrow * 4 + r;
                const int gn = n0 + wn * 64 + j * 16 + lane16;
                OUT[(size_t)gm * 1024 + gn] = acc[i][j][r];
            }
}

// ------------------------- launcher ----------------------------------------
extern "C" void kernel_launch(void* const* d_in, const int* in_sizes, int n_in,
                              void* d_out, int out_size, void* d_ws, size_t ws_size,
                              hipStream_t stream) {
    const float* x      = (const float*)d_in[0];
    const float* w_qkv  = (const float*)d_in[1];
    const float* w_out  = (const float*)d_in[2];
    const float* signs  = (const float*)d_in[3];
    const float* scales = (const float*)d_in[4];
    float* out = (float*)d_out;

    _Float16* hs = (_Float16*)d_ws;
    _Float16* xh  = hs;                       // 16,777,216
    _Float16* wh  = xh + 16777216;            // 3,145,728
    _Float16* wob = wh + 3145728;             // 1,048,576
    _Float16* kb  = wob + 1048576;            // 16,777,216  (qb overlays)
    _Float16* vb  = kb + 16777216;            // 16,777,216  (oh overlays)
    _Float16* atf = vb + 16777216;            // 262,144
    _Float16* stb = atf + 262144;             // 1,310,720
    float* St   = (float*)(stb + 1310720);    // 1,048,576
    float* sumk = St + 1048576;               // 16,384
    float* nq   = sumk + 16384;               // 262,144
    float* nk   = nq + 262144;                // 262,144
    float* MG   = nk + 262144;                // 64
    _Float16* qb = kb;                        // overlay (kb dead after kvstats)
    _Float16* oh = vb;                        // overlay (vb dead after kvstats)

    k_pre<<<dim3(2112), dim3(256), 0, stream>>>(x, w_qkv, w_out, xh, wh, wob, St,
                                                signs, scales, atf);
    // pass 1: K,V (cols 1024..3071)
    k_qkv_f16<<<dim3(2048), dim3(256), 0, stream>>>(xh, wh, qb, kb, vb, nq, nk, 1024, 16, 2048);
    k_kvstats<<<dim3(64, 8), dim3(256), 0, stream>>>(kb, vb, nk, atf, MG, St, sumk);
    // pass 2 (Q) || cvt_st
    k_mid<<<dim3(1280), dim3(256), 0, stream>>>(xh, wh, qb, kb, vb, nq, nk, St, sumk, stb);
    k_attn<<<dim3(64, 64), dim3(256), 0, stream>>>(qb, nq, atf, stb, MG, oh);
    k_outgemm<<<dim3(1024), dim3(256), 0, stream>>>(oh, wob, out);
}